// Round 12
// baseline (394.269 us; speedup 1.0000x reference)
//
#include <hip/hip_runtime.h>
#include <hip/hip_bf16.h>

typedef short bh8 __attribute__((ext_vector_type(8)));      // 8 bf16 (4 VGPR) MFMA frag
typedef float f32x4 __attribute__((ext_vector_type(4)));
typedef float f32x16 __attribute__((ext_vector_type(16)));
typedef float f2 __attribute__((ext_vector_type(2)));
typedef unsigned int uint4v __attribute__((ext_vector_type(4)));

#define GLOBAL_P(p) ((const __attribute__((address_space(1))) void*)(p))
#define LDS_P(p)    ((__attribute__((address_space(3))) void*)(p))

__device__ inline bh8 pack8(const float4& a, const float4& b) {
    union { bh8 v; __hip_bfloat16 h[8]; } u;
    u.h[0] = __float2bfloat16(a.x); u.h[1] = __float2bfloat16(a.y);
    u.h[2] = __float2bfloat16(a.z); u.h[3] = __float2bfloat16(a.w);
    u.h[4] = __float2bfloat16(b.x); u.h[5] = __float2bfloat16(b.y);
    u.h[6] = __float2bfloat16(b.z); u.h[7] = __float2bfloat16(b.w);
    return u.v;
}

// ---------------------------------------------------------------------------
// cvt3: f32 -> bf16 for q,k,v (equal sizes). 8 elems/thread/tensor.
// ---------------------------------------------------------------------------
__global__ __launch_bounds__(256) void cvt3(
    const float* __restrict__ a, const float* __restrict__ b, const float* __restrict__ c,
    __hip_bfloat16* __restrict__ oa, __hip_bfloat16* __restrict__ ob, __hip_bfloat16* __restrict__ oc)
{
    size_t i = ((size_t)blockIdx.x * 256 + threadIdx.x) * 8;
    float4 x0 = *(const float4*)(a + i), x1 = *(const float4*)(a + i + 4);
    *(bh8*)(oa + i) = pack8(x0, x1);
    float4 y0 = *(const float4*)(b + i), y1 = *(const float4*)(b + i + 4);
    *(bh8*)(ob + i) = pack8(y0, y1);
    float4 z0 = *(const float4*)(c + i), z1 = *(const float4*)(c + i + 4);
    *(bh8*)(oc + i) = pack8(z0, z1);
}

// cvtW: 4 weight matrices f32 -> bf16 into one contiguous ws region.
__global__ __launch_bounds__(256) void cvtW(
    const float* __restrict__ a, const float* __restrict__ b,
    const float* __restrict__ c, const float* __restrict__ d,
    __hip_bfloat16* __restrict__ o)
{
    int seg = blockIdx.x >> 9;                       // 512 blocks per 1M-elem segment
    const float* src = (seg == 0) ? a : (seg == 1) ? b : (seg == 2) ? c : d;
    size_t i = ((size_t)(blockIdx.x & 511) * 256 + threadIdx.x) * 8;
    float4 x0 = *(const float4*)(src + i), x1 = *(const float4*)(src + i + 4);
    *(bh8*)(o + (size_t)seg * 1048576 + i) = pack8(x0, x1);
}

// ---------------------------------------------------------------------------
// transpV: Vw[B*S,E] bf16 (token-major) -> Vt[bh][d=64][kv=2048] bf16.
// 64x64 LDS tile, pad 66. Grid 2048 = 64bh x 32kvb.
// ---------------------------------------------------------------------------
__global__ __launch_bounds__(256) void transpV(
    const __hip_bfloat16* __restrict__ Vw, __hip_bfloat16* __restrict__ Vt)
{
    __shared__ __hip_bfloat16 tile[64][66];
    const int tid = threadIdx.x;
    const int bh = blockIdx.x >> 5, kvb = blockIdx.x & 31;
    const int b = bh >> 4, h = bh & 15;
    {
        const int r = tid >> 2, c0 = (tid & 3) * 16;   // r = kv_local, c = d
        const __hip_bfloat16* src = Vw + (size_t)(b * 2048 + kvb * 64 + r) * 1024 + h * 64 + c0;
        bh8 v0 = *(const bh8*)src;
        bh8 v1 = *(const bh8*)(src + 8);
#pragma unroll
        for (int j = 0; j < 8; ++j) {
            tile[r][c0 + j]     = ((const __hip_bfloat16*)&v0)[j];
            tile[r][c0 + 8 + j] = ((const __hip_bfloat16*)&v1)[j];
        }
    }
    __syncthreads();
    {
        const int d = tid >> 2, k0 = (tid & 3) * 16;
        union { bh8 v; __hip_bfloat16 h8[8]; } o0, o1;
#pragma unroll
        for (int j = 0; j < 8; ++j) {
            o0.h8[j] = tile[k0 + j][d];
            o1.h8[j] = tile[k0 + 8 + j][d];
        }
        __hip_bfloat16* dst = Vt + ((size_t)bh * 64 + d) * 2048 + kvb * 64 + k0;
        *(bh8*)dst = o0.v;
        *(bh8*)(dst + 8) = o1.v;
    }
}

// ---------------------------------------------------------------------------
// GEMM: C[M,N] = (A[M,K] @ W[N,K]^T + bias) * oscale. A,W bf16, bias f32,
// C f32 or bf16. 128x128 tile, BK=64, 4 waves, mfma_f32_16x16x32_bf16,
// both operands staged via global_load_lds width=16 (m97 structure).
// ---------------------------------------------------------------------------
template <typename TC>
__global__ __launch_bounds__(256) void gemm_bt(
    const __hip_bfloat16* __restrict__ A, const __hip_bfloat16* __restrict__ W,
    const float* __restrict__ bias, TC* __restrict__ C,
    int M, int N, int Ksz, float oscale)
{
    __shared__ __hip_bfloat16 As[128 * 64];
    __shared__ __hip_bfloat16 Bs[128 * 64];
    const int tid = threadIdx.x;
    const int l = tid & 63, w = tid >> 6;
    const int g4 = l >> 4, rl = l & 15;
    const int nb = N >> 7;
    const int bm = blockIdx.x / nb, bn = blockIdx.x % nb;
    const long m0 = (long)bm * 128, n0 = (long)bn * 128;

    const __hip_bfloat16* ag[4];
    const __hip_bfloat16* wg[4];
    int ldsbase[4];
#pragma unroll
    for (int i = 0; i < 4; ++i) {
        int c = i * 256 + tid;           // chunk 0..1023
        int row = c >> 3, c8 = c & 7;
        ag[i] = A + (m0 + row) * Ksz + c8 * 8;
        wg[i] = W + (n0 + row) * Ksz + c8 * 8;
        ldsbase[i] = (i * 256 + w * 64) * 8;  // wave-uniform glds base (elements)
    }

    const int wr = w >> 1, wc = w & 1;
    f32x4 acc[4][4];
#pragma unroll
    for (int i = 0; i < 4; ++i)
#pragma unroll
        for (int j = 0; j < 4; ++j) acc[i][j] = f32x4{0.f, 0.f, 0.f, 0.f};

    const int nk = Ksz >> 6;
    for (int t = 0; t < nk; ++t) {
        __syncthreads();   // previous tile's LDS reads complete
#pragma unroll
        for (int i = 0; i < 4; ++i) {
            __builtin_amdgcn_global_load_lds(GLOBAL_P(ag[i]), LDS_P((__hip_bfloat16*)As + ldsbase[i]), 16, 0, 0);
            __builtin_amdgcn_global_load_lds(GLOBAL_P(wg[i]), LDS_P((__hip_bfloat16*)Bs + ldsbase[i]), 16, 0, 0);
            ag[i] += 64; wg[i] += 64;
        }
        __syncthreads();   // staged (barrier drains vmcnt)
#pragma unroll
        for (int kc = 0; kc < 2; ++kc) {
            bh8 af[4], bf[4];
#pragma unroll
            for (int mt = 0; mt < 4; ++mt) {
                int row = wr * 64 + mt * 16 + rl;
                af[mt] = *(const bh8*)(As + row * 64 + 8 * g4 + 32 * kc);
            }
#pragma unroll
            for (int nt = 0; nt < 4; ++nt) {
                int row = wc * 64 + nt * 16 + rl;
                bf[nt] = *(const bh8*)(Bs + row * 64 + 8 * g4 + 32 * kc);
            }
#pragma unroll
            for (int mt = 0; mt < 4; ++mt)
#pragma unroll
                for (int nt = 0; nt < 4; ++nt)
                    acc[mt][nt] = __builtin_amdgcn_mfma_f32_16x16x32_bf16(af[mt], bf[nt], acc[mt][nt], 0, 0, 0);
        }
    }

    // epilogue: (acc + bias) * oscale. C/D: col=lane&15, row=(lane>>4)*4+reg
    float bv[4];
#pragma unroll
    for (int nt = 0; nt < 4; ++nt)
        bv[nt] = bias[n0 + wc * 64 + nt * 16 + rl];
#pragma unroll
    for (int mt = 0; mt < 4; ++mt) {
#pragma unroll
        for (int r = 0; r < 4; ++r) {
            long row = m0 + wr * 64 + mt * 16 + g4 * 4 + r;
            TC* cp = C + row * N + n0 + wc * 64 + rl;
#pragma unroll
            for (int nt = 0; nt < 4; ++nt) {
                float x = (acc[mt][nt][r] + bv[nt]) * oscale;
                if constexpr (__is_same(TC, float)) cp[nt * 16] = x;
                else cp[nt * 16] = __float2bfloat16(x);
            }
        }
    }
}

// ---------------------------------------------------------------------------
// Flash attention, B=4 H=16 S=2048 D=64. Q pre-scaled by 0.125*log2(e).
// 4 waves x 64 q-rows each (two 32-row groups A/B), QB=256, KVBLK=64,
// 32 iters, grid 512. Residency is pinned at 2 waves/SIMD by VGPR quantum
// (r7-r11 sweep) -> amortize per-iter fixed costs (barrier, staging, serial
// chains) over 2x work per wave; A/B give independent dual chains for ILP.
// K and V^T tiles staged via global_load_lds, swizzle j^(r&7)^(r>>3);
// V^T precomputed by transpV. Double-buffered; ONE barrier per iter.
// Swapped QK^T -> in-register softmax (log2 domain, packed f32, per-group
// m/l state, shuffle-free steady state, defer-max T13).
// ---------------------------------------------------------------------------
#define THRL 11.0f                 /* defer-max threshold, log2 units */

__global__ __launch_bounds__(256, 2) void attn_kernel(
    const __hip_bfloat16* __restrict__ Qm, const __hip_bfloat16* __restrict__ Km,
    const __hip_bfloat16* __restrict__ Vt_g, const int* __restrict__ mask,
    __hip_bfloat16* __restrict__ Om)
{
    __shared__ __hip_bfloat16 Kt[2][64 * 64];   // K tile double buffer (xor-swizzled slots)
    __shared__ __hip_bfloat16 Vt[2][64 * 64];   // V^T tile double buffer (same swizzle)
    __shared__ float biasS[2048];               // mask bias for this batch
    const int tid = threadIdx.x;
    const int w = tid >> 6, l = tid & 63;
    const int G = l >> 5, c = l & 31;
    // XCD swizzle: 64 blocks per XCD = 8 bh x 8 qb
    const int id = blockIdx.x;
    const int xcd = id & 7, slot = id >> 3;
    const int bh = xcd * 8 + (slot >> 3);
    const int qb = slot & 7;
    const int b = bh >> 4, h = bh & 15;
    const int q0 = qb * 256 + w * 64;           // wave owns rows [q0, q0+64)

#pragma unroll
    for (int i = 0; i < 8; ++i) {
        int idx = i * 256 + tid;
        biasS[idx] = (mask[b * 2048 + idx] != 0) ? 0.f : -1e30f;
    }

    // Q B-frags for groups A (rows q0+c) and B (rows q0+32+c). Pre-scaled.
    const __hip_bfloat16* qpA = Qm + (size_t)(b * 2048 + q0 + c) * 1024 + h * 64 + 8 * G;
    const __hip_bfloat16* qpB = qpA + (size_t)32 * 1024;
    bh8 qfA[4], qfB[4];
#pragma unroll
    for (int kc = 0; kc < 4; ++kc) {
        qfA[kc] = *(const bh8*)(qpA + 16 * kc);
        qfB[kc] = *(const bh8*)(qpB + 16 * kc);
    }

    // glds sources: LDS[r][8j] = src_row(r)[8*(j ^ (r&7) ^ (r>>3))].
    // inst (w,i): rows r = 16w+8i+(l>>3); r&7 = l>>3, r>>3 = 2w+i (uniform).
    const int l38 = l >> 3, lc8 = l & 7;
    const __hip_bfloat16* kg0 = Km + (size_t)(b * 2048 + 16 * w + l38) * 1024 + h * 64 + 8 * ((lc8 ^ l38 ^ (2 * w)) & 7);
    const __hip_bfloat16* kg1 = Km + (size_t)(b * 2048 + 16 * w + 8 + l38) * 1024 + h * 64 + 8 * ((lc8 ^ l38 ^ (2 * w + 1)) & 7);
    const __hip_bfloat16* vg0 = Vt_g + ((size_t)bh * 64 + 16 * w + l38) * 2048 + 8 * ((lc8 ^ l38 ^ (2 * w)) & 7);
    const __hip_bfloat16* vg1 = Vt_g + ((size_t)bh * 64 + 16 * w + 8 + l38) * 2048 + 8 * ((lc8 ^ l38 ^ (2 * w + 1)) & 7);
    const int kbase_e = w * 1024;               // LDS elem base for inst (w,0); (w,1): +512

    auto stageKV = [&](int buf, int tt) {
        const size_t ko = (size_t)tt * 64 * 1024;   // K: advance 64 token rows
        const size_t vo = (size_t)tt * 64;          // V^T: advance 64 kv cols
        __builtin_amdgcn_global_load_lds(GLOBAL_P(kg0 + ko), LDS_P(&Kt[buf][0] + kbase_e), 16, 0, 0);
        __builtin_amdgcn_global_load_lds(GLOBAL_P(kg1 + ko), LDS_P(&Kt[buf][0] + kbase_e + 512), 16, 0, 0);
        __builtin_amdgcn_global_load_lds(GLOBAL_P(vg0 + vo), LDS_P(&Vt[buf][0] + kbase_e), 16, 0, 0);
        __builtin_amdgcn_global_load_lds(GLOBAL_P(vg1 + vo), LDS_P(&Vt[buf][0] + kbase_e + 512), 16, 0, 0);
    };

    // prologue
    stageKV(0, 0);
    __syncthreads();   // drains glds

    f32x16 oA0 = {0.f}, oA1 = {0.f}, oB0 = {0.f}, oB1 = {0.f};
    float mA = -1e29f, lA = 0.f;   // per-group running max / HALF-row sum
    float mB = -1e29f, lB = 0.f;

    for (int t = 0; t < 32; ++t) {
        const int buf = t & 1;
        if (t < 31) stageKV(buf ^ 1, t + 1);
        __builtin_amdgcn_sched_barrier(0);

        // QK^T from LDS: K frag read once, used for A and B
        const __hip_bfloat16* kbuf = &Kt[buf][0];
        const int kx0 = ((c & 7) ^ (c >> 3)) << 3;
        const int kx1 = kx0 ^ 32;
        f32x16 sA0 = {0.f}, sA1 = {0.f}, sB0 = {0.f}, sB1 = {0.f};
        __builtin_amdgcn_s_setprio(1);
#pragma unroll
        for (int kc = 0; kc < 4; ++kc) {
            bh8 kf = *(const bh8*)(kbuf + c * 64 + ((16 * kc + 8 * G) ^ kx0));
            sA0 = __builtin_amdgcn_mfma_f32_32x32x16_bf16(kf, qfA[kc], sA0, 0, 0, 0);
            sB0 = __builtin_amdgcn_mfma_f32_32x32x16_bf16(kf, qfB[kc], sB0, 0, 0, 0);
        }
#pragma unroll
        for (int kc = 0; kc < 4; ++kc) {
            bh8 kf = *(const bh8*)(kbuf + (c + 32) * 64 + ((16 * kc + 8 * G) ^ kx1));
            sA1 = __builtin_amdgcn_mfma_f32_32x32x16_bf16(kf, qfA[kc], sA1, 0, 0, 0);
            sB1 = __builtin_amdgcn_mfma_f32_32x32x16_bf16(kf, qfB[kc], sB1, 0, 0, 0);
        }
        __builtin_amdgcn_s_setprio(0);

        // softmax: bias + max (A and B chains independent)
        f2 mxA2 = {-1e30f, -1e30f}, mxB2 = {-1e30f, -1e30f};
        {
            f2* a0 = (f2*)&sA0; f2* a1 = (f2*)&sA1;
            f2* b0 = (f2*)&sB0; f2* b1 = (f2*)&sB1;
#pragma unroll
            for (int i2 = 0; i2 < 8; ++i2) {
                const int i = i2 * 2;
                const int boff = t * 64 + (i >> 2) * 8 + 4 * G + (i & 3);
                f2 bb0 = *(const f2*)&biasS[boff];
                f2 bb1 = *(const f2*)&biasS[boff + 32];
                f2 va0 = a0[i2] + bb0, va1 = a1[i2] + bb1;
                f2 vb0 = b0[i2] + bb0, vb1 = b1[i2] + bb1;
                a0[i2] = va0; a1[i2] = va1; b0[i2] = vb0; b1[i2] = vb1;
                mxA2 = __builtin_elementwise_max(mxA2, __builtin_elementwise_max(va0, va1));
                mxB2 = __builtin_elementwise_max(mxB2, __builtin_elementwise_max(vb0, vb1));
            }
        }
        float mxA = fmaxf(mxA2[0], mxA2[1]);
        float mxB = fmaxf(mxB2[0], mxB2[1]);

        if (__all(fmaxf(mxA - mA, mxB - mB) <= THRL)) {
            // defer-max: no rescale, P bounded by 2^THRL
            f2 lsA = {0.f, 0.f}, lsB = {0.f, 0.f};
            f2 mA2 = {mA, mA}, mB2 = {mB, mB};
            f2* a0 = (f2*)&sA0; f2* a1 = (f2*)&sA1;
            f2* b0 = (f2*)&sB0; f2* b1 = (f2*)&sB1;
#pragma unroll
            for (int i2 = 0; i2 < 8; ++i2) {
                f2 eA0 = a0[i2] - mA2, eA1 = a1[i2] - mA2;
                f2 eB0 = b0[i2] - mB2, eB1 = b1[i2] - mB2;
                f2 pA0, pA1, pB0, pB1;
                pA0[0] = __builtin_amdgcn_exp2f(eA0[0]); pA0[1] = __builtin_amdgcn_exp2f(eA0[1]);
                pA1[0] = __builtin_amdgcn_exp2f(eA1[0]); pA1[1] = __builtin_amdgcn_exp2f(eA1[1]);
                pB0[0] = __builtin_amdgcn_exp2f(eB0[0]); pB0[1] = __builtin_amdgcn_exp2f(eB0[1]);
                pB1[0] = __builtin_amdgcn_exp2f(eB1[0]); pB1[1] = __builtin_amdgcn_exp2f(eB1[1]);
                a0[i2] = pA0; a1[i2] = pA1; b0[i2] = pB0; b1[i2] = pB1;
                lsA += pA0 + pA1; lsB += pB0 + pB1;
            }
            lA += lsA[0] + lsA[1];
            lB += lsB[0] + lsB[1];
        } else {
            float mxfA = fmaxf(mxA, __shfl_xor(mxA, 32));
            float mxfB = fmaxf(mxB, __shfl_xor(mxB, 32));
            const float mnA = fmaxf(mA, mxfA), mnB = fmaxf(mB, mxfB);
            const float facA = __builtin_amdgcn_exp2f(mA - mnA);
            const float facB = __builtin_amdgcn_exp2f(mB - mnB);
            f2 lsA = {0.f, 0.f}, lsB = {0.f, 0.f};
            f2 mA2 = {mnA, mnA}, mB2 = {mnB, mnB};
            f2* a0 = (f2*)&sA0; f2* a1 = (f2*)&sA1;
            f2* b0 = (f2*)&sB0; f2* b1 = (f2*)&sB1;
#pragma unroll
            for (int i2 = 0; i2 < 8; ++i2) {
                f2 eA0 = a0[i2] - mA2, eA1 = a1[i2] - mA2;
                f2 eB0 = b0[i2] - mB2, eB1 = b1[i2] - mB2;
                f2 pA0, pA1, pB0, pB1;
                pA0[0] = __builtin_amdgcn_exp2f(eA0[0]); pA0[1] = __builtin_amdgcn_exp2f(eA0[1]);
                pA1[0] = __builtin_amdgcn_exp2f(eA1[0]); pA1[1] = __builtin_amdgcn_exp2f(eA1[1]);
                pB0[0] = __builtin_amdgcn_exp2f(eB0[0]); pB0[1] = __builtin_amdgcn_exp2f(eB0[1]);
                pB1[0] = __builtin_amdgcn_exp2f(eB1[0]); pB1[1] = __builtin_amdgcn_exp2f(eB1[1]);
                a0[i2] = pA0; a1[i2] = pA1; b0[i2] = pB0; b1[i2] = pB1;
                lsA += pA0 + pA1; lsB += pB0 + pB1;
            }
            lA = lA * facA + (lsA[0] + lsA[1]);
            lB = lB * facB + (lsB[0] + lsB[1]);
            mA = mnA; mB = mnB;
            f2 fA = {facA, facA}, fB = {facB, facB};
            f2* oA0p = (f2*)&oA0; f2* oA1p = (f2*)&oA1;
            f2* oB0p = (f2*)&oB0; f2* oB1p = (f2*)&oB1;
#pragma unroll
            for (int i2 = 0; i2 < 8; ++i2) {
                oA0p[i2] *= fA; oA1p[i2] *= fA;
                oB0p[i2] *= fB; oB1p[i2] *= fB;
            }
        }

        // PV: V frag read once, used for A and B
        const __hip_bfloat16* vbuf = &Vt[buf][0];
#pragma unroll
        for (int sl = 0; sl < 4; ++sl) {
            const int kvb = 16 * sl + 8 * G;
            bh8 vf0 = *(const bh8*)(vbuf + c * 64 + (kvb ^ ((c & 7) ^ (c >> 3)) * 8));
            bh8 vf1 = *(const bh8*)(vbuf + (c + 32) * 64 + (kvb ^ (((c & 7) ^ (c >> 3)) * 8) ^ 32));
            // group A pack
            {
                const f32x16& ps = (sl < 2) ? sA0 : sA1;
                const int R0 = 8 * (sl & 1);
                unsigned a0, a1, b0, b1;
                asm("v_cvt_pk_bf16_f32 %0, %1, %2" : "=v"(a0) : "v"(ps[R0 + 0]), "v"(ps[R0 + 1]));
                asm("v_cvt_pk_bf16_f32 %0, %1, %2" : "=v"(a1) : "v"(ps[R0 + 2]), "v"(ps[R0 + 3]));
                asm("v_cvt_pk_bf16_f32 %0, %1, %2" : "=v"(b0) : "v"(ps[R0 + 4]), "v"(ps[R0 + 5]));
                asm("v_cvt_pk_bf16_f32 %0, %1, %2" : "=v"(b1) : "v"(ps[R0 + 6]), "v"(ps[R0 + 7]));
                asm("v_permlane32_swap_b32 %0, %1" : "+v"(a0), "+v"(b0));
                asm("v_permlane32_swap_b32 %0, %1" : "+v"(a1), "+v"(b1));
                uint4v pu = {a0, a1, b0, b1};
                bh8 pf = __builtin_bit_cast(bh8, pu);
                __builtin_amdgcn_s_setprio(1);
                oA0 = __builtin_amdgcn_mfma_f32_32x32x16_bf16(vf0, pf, oA0, 0, 0, 0);
                oA1 = __builtin_amdgcn_mfma_f32_32x32x16_bf16(vf1, pf, oA1, 0, 0, 0);
                __builtin_amdgcn_s_setprio(0);
            }
            // group B pack
            {
                const f32x16& ps = (sl < 2) ? sB0 : sB1;
                const int R0 = 8 * (sl & 1);
                unsigned a0, a1, b0, b1;
                asm("v_cvt_pk_bf16_f32 %0, %1, %2" : "=v"(a0) : "v"(ps[R0 + 0]), "v"(ps[R0 + 1]));
                asm("v_cvt_pk_bf16_f32 %0, %1, %2" : "=v"(a1) : "v"(ps[R0 + 2]), "v"(ps[R0 + 3]));
                asm("v_cvt_pk_bf16_f32 %0, %1, %2" : "=v"(b0) : "v"(ps[R0 + 4]), "v"(ps[R0 + 5]));
                asm("v_cvt_pk_bf16_f32 %0, %1, %2" : "=v"(b1) : "v"(ps[R0 + 6]), "v"(ps[R0 + 7]));
                asm("v_permlane32_swap_b32 %0, %1" : "+v"(a0), "+v"(b0));
                asm("v_permlane32_swap_b32 %0, %1" : "+v"(a1), "+v"(b1));
                uint4v pu = {a0, a1, b0, b1};
                bh8 pf = __builtin_bit_cast(bh8, pu);
                __builtin_amdgcn_s_setprio(1);
                oB0 = __builtin_amdgcn_mfma_f32_32x32x16_bf16(vf0, pf, oB0, 0, 0, 0);
                oB1 = __builtin_amdgcn_mfma_f32_32x32x16_bf16(vf1, pf, oB1, 0, 0, 0);
                __builtin_amdgcn_s_setprio(0);
            }
        }

        __syncthreads();   // buf reads done; buf^1 staging drained
    }

    // epilogue: combine half-row sums, O = acc/l (l==0 -> 0), packed stores
    float ltA = lA + __shfl_xor(lA, 32);
    float ltB = lB + __shfl_xor(lB, 32);
    float invA = (ltA > 0.f) ? 1.f / ltA : 0.f;
    float invB = (ltB > 0.f) ? 1.f / ltB : 0.f;
    __hip_bfloat16* opA = Om + (size_t)(b * 2048 + q0 + c) * 1024 + h * 64 + 4 * G;
    __hip_bfloat16* opB = opA + (size_t)32 * 1024;
#pragma unroll
    for (int dt = 0; dt < 2; ++dt) {
#pragma unroll
        for (int rb = 0; rb < 4; ++rb) {
            union { ushort4 u; __hip_bfloat16 hv[4]; } cA, cB;
#pragma unroll
            for (int j = 0; j < 4; ++j) {
                float xA = (dt ? oA1[rb * 4 + j] : oA0[rb * 4 + j]) * invA;
                float xB = (dt ? oB1[rb * 4 + j] : oB0[rb * 4 + j]) * invB;
                cA.hv[j] = __float2bfloat16(xA);
                cB.hv[j] = __float2bfloat16(xB);
            }
            *(ushort4*)(opA + dt * 32 + rb * 8) = cA.u;
            *(ushort4*)(opB + dt * 32 + rb * 8) = cB.u;
        }
    }
}

// ---------------------------------------------------------------------------
extern "C" void kernel_launch(void* const* d_in, const int* in_sizes, int n_in,
                              void* d_out, int out_size, void* d_ws, size_t ws_size,
                              hipStream_t stream) {
    const float* q  = (const float*)d_in[0];
    const float* k  = (const float*)d_in[1];
    const float* v  = (const float*)d_in[2];
    const int*   mk = (const int*)d_in[3];
    const float* Wq = (const float*)d_in[4];
    const float* bq = (const float*)d_in[5];
    const float* Wk = (const float*)d_in[6];
    const float* bk = (const float*)d_in[7];
    const float* Wv = (const float*)d_in[8];
    const float* bv = (const float*)d_in[9];
    const float* Wo = (const float*)d_in[10];
    const float* bo = (const float*)d_in[11];
    float* out = (float*)d_out;

    const float CSC = 0.18033688011112042f;      // 0.125 * log2(e), folded into Q
    const size_t MN = (size_t)8192 * 1024;
    const size_t WN = (size_t)1024 * 1024;
    __hip_bfloat16* B0 = (__hip_bfloat16*)d_ws;  // q_bf -> Kw
    __hip_bfloat16* B1 = B0 + MN;                // k_bf -> Vw
    __hip_bfloat16* B2 = B1 + MN;                // v_bf -> Ow
    __hip_bfloat16* B3 = B2 + MN;                // Qw (pre-scaled)
    __hip_bfloat16* Wb = B3 + MN;                // Wq,Wk,Wv,Wo bf16 (1M elems each)
    __hip_bfloat16* Vt = Wb + 4 * WN;            // V^T [bh][64][2048]

    cvt3<<<4096, 256, 0, stream>>>(q, k, v, B0, B1, B2);
    cvtW<<<2048, 256, 0, stream>>>(Wq, Wk, Wv, Wo, Wb);
    gemm_bt<__hip_bfloat16><<<512, 256, 0, stream>>>(B0, Wb,          bq, B3, 8192, 1024, 1024, CSC);  // Qw=B3
    gemm_bt<__hip_bfloat16><<<512, 256, 0, stream>>>(B1, Wb + WN,     bk, B0, 8192, 1024, 1024, 1.0f); // Kw=B0
    gemm_bt<__hip_bfloat16><<<512, 256, 0, stream>>>(B2, Wb + 2 * WN, bv, B1, 8192, 1024, 1024, 1.0f); // Vw=B1
    transpV<<<2048, 256, 0, stream>>>(B1, Vt);                                                          // Vw -> V^T
    attn_kernel<<<512, 256, 0, stream>>>(B3, B0, Vt, mk, B2);                                           // Ow=B2
    gemm_bt<float><<<512, 256, 0, stream>>>(B2, Wb + 3 * WN, bo, out, 8192, 1024, 1024, 1.0f);
}

// Round 13
// 237.830 us; speedup vs baseline: 1.6578x; 1.6578x over previous
//
#include <hip/hip_runtime.h>
#include <hip/hip_bf16.h>

typedef short bh8 __attribute__((ext_vector_type(8)));      // 8 bf16 (4 VGPR) MFMA frag
typedef float f32x4 __attribute__((ext_vector_type(4)));
typedef float f32x16 __attribute__((ext_vector_type(16)));
typedef float f2 __attribute__((ext_vector_type(2)));
typedef unsigned int uint4v __attribute__((ext_vector_type(4)));

#define GLOBAL_P(p) ((const __attribute__((address_space(1))) void*)(p))
#define LDS_P(p)    ((__attribute__((address_space(3))) void*)(p))

__device__ inline bh8 pack8(const float4& a, const float4& b) {
    union { bh8 v; __hip_bfloat16 h[8]; } u;
    u.h[0] = __float2bfloat16(a.x); u.h[1] = __float2bfloat16(a.y);
    u.h[2] = __float2bfloat16(a.z); u.h[3] = __float2bfloat16(a.w);
    u.h[4] = __float2bfloat16(b.x); u.h[5] = __float2bfloat16(b.y);
    u.h[6] = __float2bfloat16(b.z); u.h[7] = __float2bfloat16(b.w);
    return u.v;
}

// ---------------------------------------------------------------------------
// cvt3: f32 -> bf16 for q,k,v (equal sizes). 8 elems/thread/tensor.
// ---------------------------------------------------------------------------
__global__ __launch_bounds__(256) void cvt3(
    const float* __restrict__ a, const float* __restrict__ b, const float* __restrict__ c,
    __hip_bfloat16* __restrict__ oa, __hip_bfloat16* __restrict__ ob, __hip_bfloat16* __restrict__ oc)
{
    size_t i = ((size_t)blockIdx.x * 256 + threadIdx.x) * 8;
    float4 x0 = *(const float4*)(a + i), x1 = *(const float4*)(a + i + 4);
    *(bh8*)(oa + i) = pack8(x0, x1);
    float4 y0 = *(const float4*)(b + i), y1 = *(const float4*)(b + i + 4);
    *(bh8*)(ob + i) = pack8(y0, y1);
    float4 z0 = *(const float4*)(c + i), z1 = *(const float4*)(c + i + 4);
    *(bh8*)(oc + i) = pack8(z0, z1);
}

// cvtW: 4 weight matrices f32 -> bf16 into one contiguous ws region.
__global__ __launch_bounds__(256) void cvtW(
    const float* __restrict__ a, const float* __restrict__ b,
    const float* __restrict__ c, const float* __restrict__ d,
    __hip_bfloat16* __restrict__ o)
{
    int seg = blockIdx.x >> 9;                       // 512 blocks per 1M-elem segment
    const float* src = (seg == 0) ? a : (seg == 1) ? b : (seg == 2) ? c : d;
    size_t i = ((size_t)(blockIdx.x & 511) * 256 + threadIdx.x) * 8;
    float4 x0 = *(const float4*)(src + i), x1 = *(const float4*)(src + i + 4);
    *(bh8*)(o + (size_t)seg * 1048576 + i) = pack8(x0, x1);
}

// ---------------------------------------------------------------------------
// maskScan: per batch, exclusive-scan the valid mask -> compact index list
// idx[b][pos] = kv, nv[b] = count. 4 blocks x 256 thr, 8 mask vals/thread.
// ---------------------------------------------------------------------------
__global__ __launch_bounds__(256) void maskScan(
    const int* __restrict__ mask, int* __restrict__ idx, int* __restrict__ nv)
{
    __shared__ int ts[256];
    const int b = blockIdx.x, tid = threadIdx.x;
    int f[8], cnt = 0;
#pragma unroll
    for (int j = 0; j < 8; ++j) {
        f[j] = (mask[b * 2048 + tid * 8 + j] != 0) ? 1 : 0;
        cnt += f[j];
    }
    ts[tid] = cnt;
    __syncthreads();
    for (int off = 1; off < 256; off <<= 1) {
        int v = (tid >= off) ? ts[tid - off] : 0;
        __syncthreads();
        ts[tid] += v;
        __syncthreads();
    }
    int base = ts[tid] - cnt;   // exclusive prefix
#pragma unroll
    for (int j = 0; j < 8; ++j)
        if (f[j]) idx[b * 2048 + base++] = tid * 8 + j;
    if (tid == 255) nv[b] = ts[255];
}

// ---------------------------------------------------------------------------
// gatherKV: compact K/V rows per batch (pad to x64 with zeros).
// Grid 128 = 4b x 32 row-blocks; 4 threads/row, 512B chunks.
// ---------------------------------------------------------------------------
__global__ __launch_bounds__(256) void gatherKV(
    const __hip_bfloat16* __restrict__ Kw, const __hip_bfloat16* __restrict__ Vw,
    const int* __restrict__ idx, const int* __restrict__ nv,
    __hip_bfloat16* __restrict__ Kc, __hip_bfloat16* __restrict__ Vc)
{
    const int b = blockIdx.x >> 5, j = blockIdx.x & 31;
    const int n = nv[b], npad = (n + 63) & ~63;
    const int r = j * 64 + (threadIdx.x >> 2);
    if (r >= npad) return;
    const int c0 = (threadIdx.x & 3) * 256;
    __hip_bfloat16* dk = Kc + ((size_t)b * 2048 + r) * 1024 + c0;
    __hip_bfloat16* dv = Vc + ((size_t)b * 2048 + r) * 1024 + c0;
    if (r < n) {
        const int s = idx[b * 2048 + r];
        const __hip_bfloat16* sk = Kw + ((size_t)b * 2048 + s) * 1024 + c0;
        const __hip_bfloat16* sv = Vw + ((size_t)b * 2048 + s) * 1024 + c0;
#pragma unroll
        for (int i = 0; i < 32; ++i) {
            ((bh8*)dk)[i] = ((const bh8*)sk)[i];
            ((bh8*)dv)[i] = ((const bh8*)sv)[i];
        }
    } else {
        bh8 z = {};
#pragma unroll
        for (int i = 0; i < 32; ++i) { ((bh8*)dk)[i] = z; ((bh8*)dv)[i] = z; }
    }
}

// ---------------------------------------------------------------------------
// GEMM: C[M,N] = (A[M,K] @ W[N,K]^T + bias) * oscale. A,W bf16, bias f32,
// C f32 or bf16. 128x128 tile, BK=64, 4 waves, mfma_f32_16x16x32_bf16,
// both operands staged via global_load_lds width=16 (m97 structure).
// ---------------------------------------------------------------------------
template <typename TC>
__global__ __launch_bounds__(256) void gemm_bt(
    const __hip_bfloat16* __restrict__ A, const __hip_bfloat16* __restrict__ W,
    const float* __restrict__ bias, TC* __restrict__ C,
    int M, int N, int Ksz, float oscale)
{
    __shared__ __hip_bfloat16 As[128 * 64];
    __shared__ __hip_bfloat16 Bs[128 * 64];
    const int tid = threadIdx.x;
    const int l = tid & 63, w = tid >> 6;
    const int g4 = l >> 4, rl = l & 15;
    const int nb = N >> 7;
    const int bm = blockIdx.x / nb, bn = blockIdx.x % nb;
    const long m0 = (long)bm * 128, n0 = (long)bn * 128;

    const __hip_bfloat16* ag[4];
    const __hip_bfloat16* wg[4];
    int ldsbase[4];
#pragma unroll
    for (int i = 0; i < 4; ++i) {
        int c = i * 256 + tid;           // chunk 0..1023
        int row = c >> 3, c8 = c & 7;
        ag[i] = A + (m0 + row) * Ksz + c8 * 8;
        wg[i] = W + (n0 + row) * Ksz + c8 * 8;
        ldsbase[i] = (i * 256 + w * 64) * 8;  // wave-uniform glds base (elements)
    }

    const int wr = w >> 1, wc = w & 1;
    f32x4 acc[4][4];
#pragma unroll
    for (int i = 0; i < 4; ++i)
#pragma unroll
        for (int j = 0; j < 4; ++j) acc[i][j] = f32x4{0.f, 0.f, 0.f, 0.f};

    const int nk = Ksz >> 6;
    for (int t = 0; t < nk; ++t) {
        __syncthreads();   // previous tile's LDS reads complete
#pragma unroll
        for (int i = 0; i < 4; ++i) {
            __builtin_amdgcn_global_load_lds(GLOBAL_P(ag[i]), LDS_P((__hip_bfloat16*)As + ldsbase[i]), 16, 0, 0);
            __builtin_amdgcn_global_load_lds(GLOBAL_P(wg[i]), LDS_P((__hip_bfloat16*)Bs + ldsbase[i]), 16, 0, 0);
            ag[i] += 64; wg[i] += 64;
        }
        __syncthreads();   // staged (barrier drains vmcnt)
#pragma unroll
        for (int kc = 0; kc < 2; ++kc) {
            bh8 af[4], bf[4];
#pragma unroll
            for (int mt = 0; mt < 4; ++mt) {
                int row = wr * 64 + mt * 16 + rl;
                af[mt] = *(const bh8*)(As + row * 64 + 8 * g4 + 32 * kc);
            }
#pragma unroll
            for (int nt = 0; nt < 4; ++nt) {
                int row = wc * 64 + nt * 16 + rl;
                bf[nt] = *(const bh8*)(Bs + row * 64 + 8 * g4 + 32 * kc);
            }
#pragma unroll
            for (int mt = 0; mt < 4; ++mt)
#pragma unroll
                for (int nt = 0; nt < 4; ++nt)
                    acc[mt][nt] = __builtin_amdgcn_mfma_f32_16x16x32_bf16(af[mt], bf[nt], acc[mt][nt], 0, 0, 0);
        }
    }

    // epilogue: (acc + bias) * oscale. C/D: col=lane&15, row=(lane>>4)*4+reg
    float bv[4];
#pragma unroll
    for (int nt = 0; nt < 4; ++nt)
        bv[nt] = bias[n0 + wc * 64 + nt * 16 + rl];
#pragma unroll
    for (int mt = 0; mt < 4; ++mt) {
#pragma unroll
        for (int r = 0; r < 4; ++r) {
            long row = m0 + wr * 64 + mt * 16 + g4 * 4 + r;
            TC* cp = C + row * N + n0 + wc * 64 + rl;
#pragma unroll
            for (int nt = 0; nt < 4; ++nt) {
                float x = (acc[mt][nt][r] + bv[nt]) * oscale;
                if constexpr (__is_same(TC, float)) cp[nt * 16] = x;
                else cp[nt * 16] = __float2bfloat16(x);
            }
        }
    }
}

// ---------------------------------------------------------------------------
// Flash attention over COMPACTED KV (valid columns only, zero-padded to x64).
// B=4 H=16 S=2048 D=64. Q pre-scaled by 0.125*log2(e). r8 structure:
// 4 waves x 32 q-rows (QB=128), KVBLK=64, nt=ceil(nv/64) iters (runtime),
// K via global_load_lds swizzle j^(r&7)^(r>>3); V reg->LDS transpose
// (paired u32 writes). Double-buffered; ONE barrier per iter. Swapped QK^T
// -> in-register softmax (log2, packed f32, half-row l_run, defer-max).
// Pad cols get bias -1e30 -> P=0 exactly; K/V pad rows zeroed by gatherKV.
// nt==0 (all-masked batch): loop skipped, l=0 -> O=0 (matches reference).
// ---------------------------------------------------------------------------
#define THRL 11.0f                 /* defer-max threshold, log2 units */

__global__ __launch_bounds__(256, 2) void attn_kernel(
    const __hip_bfloat16* __restrict__ Qm, const __hip_bfloat16* __restrict__ Km,
    const __hip_bfloat16* __restrict__ Vm, const int* __restrict__ nvp,
    __hip_bfloat16* __restrict__ Om)
{
    __shared__ __hip_bfloat16 Kt[2][64 * 64];   // K tile double buffer (xor-swizzled slots)
    __shared__ __hip_bfloat16 Vt[2][64 * 64];   // V^T double buffer (swizzled)
    __shared__ float biasS[2048];               // 0 for col<nv, -1e30 for pad
    const int tid = threadIdx.x;
    const int w = tid >> 6, l = tid & 63;
    const int G = l >> 5, c = l & 31;
    // XCD swizzle: xcd = id&7 owns bh = xcd*8 + (slot>>4); qb = slot&15
    const int id = blockIdx.x;
    const int xcd = id & 7, slot = id >> 3;
    const int bh = xcd * 8 + (slot >> 4);
    const int qb = slot & 15;
    const int b = bh >> 4, h = bh & 15;
    const int q0 = qb * 128 + w * 32;

    const int n = nvp[b];
    const int nt = (n + 63) >> 6;

#pragma unroll
    for (int i = 0; i < 8; ++i) {
        int idx = i * 256 + tid;
        biasS[idx] = (idx < n) ? 0.f : -1e30f;
    }

    // Q B-frags: col j = q = c, k = 8G+jj (+16*kc). (Q pre-scaled by CSC.)
    const __hip_bfloat16* qp = Qm + (size_t)(b * 2048 + q0 + c) * 1024 + h * 64 + 8 * G;
    bh8 qf[4];
#pragma unroll
    for (int kc = 0; kc < 4; ++kc) qf[kc] = *(const bh8*)(qp + 16 * kc);

    // K glds: LDS[r][8j] = global[r][8*(j ^ (r&7) ^ (r>>3))].
    // inst (w,i): rows r = 16w+8i+(l>>3); r&7 = l>>3, r>>3 = 2w+i (uniform).
    const int l38 = l >> 3, lc8 = l & 7;
    const __hip_bfloat16* kg0 = Km + (size_t)(b * 2048 + 16 * w + l38) * 1024 + h * 64 + 8 * ((lc8 ^ l38 ^ (2 * w)) & 7);
    const __hip_bfloat16* kg1 = Km + (size_t)(b * 2048 + 16 * w + 8 + l38) * 1024 + h * 64 + 8 * ((lc8 ^ l38 ^ (2 * w + 1)) & 7);
    const int kbase_e = w * 1024;               // LDS elem base for inst (w,0); (w,1): +512

    // V: thread owns rows {2vpi, 2vpi+1}, d-octet vd0..vd0+7
    const int vpi = tid >> 3, vd0 = (tid & 7) * 8;
    const __hip_bfloat16* vbase = Vm + (size_t)(b * 2048 + 2 * vpi) * 1024 + h * 64 + vd0;

    bh8 va0, va1;   // V rows 2vpi, 2vpi+1 of the prefetched tile
    auto loadV = [&](int tt) {
        const __hip_bfloat16* vp = vbase + (size_t)tt * 64 * 1024;
        va0 = *(const bh8*)vp;
        va1 = *(const bh8*)(vp + 1024);
    };
    auto stageV = [&](int buf) {
        __hip_bfloat16* dst = &Vt[buf][0];
#pragma unroll
        for (int j = 0; j < 8; ++j) {
            int d = vd0 + j;
            int swz = ((d & 7) ^ (d >> 3)) << 3;
            unsigned lo = (unsigned short)((const short*)&va0)[j];
            unsigned hi = (unsigned short)((const short*)&va1)[j];
            *(unsigned*)&dst[(d * 64 + 2 * vpi) ^ swz] = lo | (hi << 16);
        }
    };
    auto stageK = [&](int buf, int tt) {
        const size_t off = (size_t)tt * 64 * 1024;
        __builtin_amdgcn_global_load_lds(GLOBAL_P(kg0 + off), LDS_P(&Kt[buf][0] + kbase_e), 16, 0, 0);
        __builtin_amdgcn_global_load_lds(GLOBAL_P(kg1 + off), LDS_P(&Kt[buf][0] + kbase_e + 512), 16, 0, 0);
    };

    // prologue: K(0)->Kt[0]; V(0)->Vt[0]; V(1)->regs (indices clamped; in-bounds
    // even for nt<=1 since the compact buffer spans 2048 rows)
    stageK(0, 0);
    loadV(0);
    stageV(0);
    loadV(nt > 1 ? 1 : 0);
    __syncthreads();   // drains glds + LDS writes

    f32x16 o0 = {0.f}, o1 = {0.f};
    float m_run = -1e29f, l_run = 0.f;   // l_run is HALF-row (this lane's share)

    for (int t = 0; t < nt; ++t) {
        const int buf = t & 1;
        // stage next tile into buf^1; prefetch V(t+2) into regs
        if (t < nt - 1) {
            stageK(buf ^ 1, t + 1);
            stageV(buf ^ 1);               // va regs hold V(t+1)
            loadV(t + 2 < nt ? t + 2 : nt - 1);
        }
        __builtin_amdgcn_sched_barrier(0);

        // QK^T from LDS: S^T tiles D[i=kv-32ct][j=q], frag rows kv=32ct+c
        const __hip_bfloat16* kbuf = &Kt[buf][0];
        const int kx0 = ((c & 7) ^ (c >> 3)) << 3;   // row c swizzle
        const int kx1 = kx0 ^ 32;                    // row c+32: (r>>3) gains bit 2
        f32x16 s0 = {0.f}, s1 = {0.f};
        __builtin_amdgcn_s_setprio(1);
#pragma unroll
        for (int kc = 0; kc < 4; ++kc) {
            bh8 kf = *(const bh8*)(kbuf + c * 64 + ((16 * kc + 8 * G) ^ kx0));
            s0 = __builtin_amdgcn_mfma_f32_32x32x16_bf16(kf, qf[kc], s0, 0, 0, 0);
        }
#pragma unroll
        for (int kc = 0; kc < 4; ++kc) {
            bh8 kf = *(const bh8*)(kbuf + (c + 32) * 64 + ((16 * kc + 8 * G) ^ kx1));
            s1 = __builtin_amdgcn_mfma_f32_32x32x16_bf16(kf, qf[kc], s1, 0, 0, 0);
        }
        __builtin_amdgcn_s_setprio(0);

        // + pad bias, lane-local max (packed f32); Q already carries scale
        f2 mx2 = {-1e30f, -1e30f};
#pragma unroll
        for (int ct = 0; ct < 2; ++ct) {
            f2* sp = (f2*)(ct ? &s1 : &s0);
#pragma unroll
            for (int i2 = 0; i2 < 8; ++i2) {
                const int i = i2 * 2;
                f2 bb = *(const f2*)&biasS[t * 64 + ct * 32 + (i >> 2) * 8 + 4 * G + (i & 3)];
                f2 sv = sp[i2] + bb;
                sp[i2] = sv;
                mx2 = __builtin_elementwise_max(mx2, sv);
            }
        }
        float mxl = fmaxf(mx2[0], mx2[1]);

        if (__all(mxl - m_run <= THRL)) {
            // defer-max: no rescale, P bounded by 2^THRL
            f2 ls2 = {0.f, 0.f};
            f2 m2 = {m_run, m_run};
#pragma unroll
            for (int ct = 0; ct < 2; ++ct) {
                f2* sp = (f2*)(ct ? &s1 : &s0);
#pragma unroll
                for (int i2 = 0; i2 < 8; ++i2) {
                    f2 e = sp[i2] - m2;
                    f2 p;
                    p[0] = __builtin_amdgcn_exp2f(e[0]);
                    p[1] = __builtin_amdgcn_exp2f(e[1]);
                    sp[i2] = p; ls2 += p;
                }
            }
            l_run += ls2[0] + ls2[1];
        } else {
            float mxf = fmaxf(mxl, __shfl_xor(mxl, 32));
            const float m_new = fmaxf(m_run, mxf);
            const float fac = __builtin_amdgcn_exp2f(m_run - m_new);
            f2 ls2 = {0.f, 0.f};
            f2 m2 = {m_new, m_new};
#pragma unroll
            for (int ct = 0; ct < 2; ++ct) {
                f2* sp = (f2*)(ct ? &s1 : &s0);
#pragma unroll
                for (int i2 = 0; i2 < 8; ++i2) {
                    f2 e = sp[i2] - m2;
                    f2 p;
                    p[0] = __builtin_amdgcn_exp2f(e[0]);
                    p[1] = __builtin_amdgcn_exp2f(e[1]);
                    sp[i2] = p; ls2 += p;
                }
            }
            l_run = l_run * fac + (ls2[0] + ls2[1]);
            m_run = m_new;
            f2 fc = {fac, fac};
            f2* o0p = (f2*)&o0; f2* o1p = (f2*)&o1;
#pragma unroll
            for (int i2 = 0; i2 < 8; ++i2) { o0p[i2] *= fc; o1p[i2] *= fc; }
        }

        // PV: O^T += mfma(V^T-frag, P^T-frag). P^T frag built in-register.
        const __hip_bfloat16* vbuf = &Vt[buf][0];
        const int swz0 = ((c & 7) ^ (c >> 3)) << 3;
        const int swz1 = ((c & 7) ^ ((c + 32) >> 3)) << 3;
#pragma unroll
        for (int sl = 0; sl < 4; ++sl) {
            const f32x16& ps = (sl < 2) ? s0 : s1;
            const int R0 = 8 * (sl & 1);
            unsigned a0, a1, b0, b1;
            asm("v_cvt_pk_bf16_f32 %0, %1, %2" : "=v"(a0) : "v"(ps[R0 + 0]), "v"(ps[R0 + 1]));
            asm("v_cvt_pk_bf16_f32 %0, %1, %2" : "=v"(a1) : "v"(ps[R0 + 2]), "v"(ps[R0 + 3]));
            asm("v_cvt_pk_bf16_f32 %0, %1, %2" : "=v"(b0) : "v"(ps[R0 + 4]), "v"(ps[R0 + 5]));
            asm("v_cvt_pk_bf16_f32 %0, %1, %2" : "=v"(b1) : "v"(ps[R0 + 6]), "v"(ps[R0 + 7]));
            asm("v_permlane32_swap_b32 %0, %1" : "+v"(a0), "+v"(b0));
            asm("v_permlane32_swap_b32 %0, %1" : "+v"(a1), "+v"(b1));
            uint4v pu = {a0, a1, b0, b1};
            bh8 pf = __builtin_bit_cast(bh8, pu);
            const int kvb = 16 * sl + 8 * G;
            bh8 vf0 = *(const bh8*)(vbuf + c * 64 + (kvb ^ swz0));
            bh8 vf1 = *(const bh8*)(vbuf + (c + 32) * 64 + (kvb ^ swz1));
            __builtin_amdgcn_s_setprio(1);
            o0 = __builtin_amdgcn_mfma_f32_32x32x16_bf16(vf0, pf, o0, 0, 0, 0);
            o1 = __builtin_amdgcn_mfma_f32_32x32x16_bf16(vf1, pf, o1, 0, 0, 0);
            __builtin_amdgcn_s_setprio(0);
        }

        __syncthreads();   // buf reads done; buf^1 staging drained
    }

    // epilogue: combine half-row sums, O = acc/l (l==0 -> 0), packed stores
    float l_tot = l_run + __shfl_xor(l_run, 32);
    float inv = (l_tot > 0.f) ? 1.f / l_tot : 0.f;
    __hip_bfloat16* op = Om + (size_t)(b * 2048 + q0 + c) * 1024 + h * 64 + 4 * G;
#pragma unroll
    for (int dt = 0; dt < 2; ++dt) {
#pragma unroll
        for (int rb = 0; rb < 4; ++rb) {
            union { ushort4 u; __hip_bfloat16 hv[4]; } cv;
#pragma unroll
            for (int j = 0; j < 4; ++j) {
                float x = (dt ? o1[rb * 4 + j] : o0[rb * 4 + j]) * inv;
                cv.hv[j] = __float2bfloat16(x);
            }
            *(ushort4*)(op + dt * 32 + rb * 8) = cv.u;
        }
    }
}

// ---------------------------------------------------------------------------
extern "C" void kernel_launch(void* const* d_in, const int* in_sizes, int n_in,
                              void* d_out, int out_size, void* d_ws, size_t ws_size,
                              hipStream_t stream) {
    const float* q  = (const float*)d_in[0];
    const float* k  = (const float*)d_in[1];
    const float* v  = (const float*)d_in[2];
    const int*   mk = (const int*)d_in[3];
    const float* Wq = (const float*)d_in[4];
    const float* bq = (const float*)d_in[5];
    const float* Wk = (const float*)d_in[6];
    const float* bk = (const float*)d_in[7];
    const float* Wv = (const float*)d_in[8];
    const float* bv = (const float*)d_in[9];
    const float* Wo = (const float*)d_in[10];
    const float* bo = (const float*)d_in[11];
    float* out = (float*)d_out;

    const float CSC = 0.18033688011112042f;      // 0.125 * log2(e), folded into Q
    const size_t MN = (size_t)8192 * 1024;
    const size_t WN = (size_t)1024 * 1024;
    // Region plan (fits the proven r10 footprint of ~92.4 MB):
    __hip_bfloat16* R0 = (__hip_bfloat16*)d_ws;  // q_bf -> Kw -> Ow
    __hip_bfloat16* R1 = R0 + MN;                // k_bf -> Vw
    __hip_bfloat16* R2 = R1 + MN;                // v_bf -> Kc (compacted K)
    __hip_bfloat16* R3 = R2 + MN;                // Qw (pre-scaled)
    __hip_bfloat16* Wb = R3 + MN;                // Wq,Wk,Wv,Wo bf16 (4 x 1M elems)
    int* idxp = (int*)(Wb + 4 * WN);             // [4][2048] compact indices (32 KB)
    int* nvp  = idxp + 4 * 2048;                 // [4] valid counts
    __hip_bfloat16* Vc = (__hip_bfloat16*)((char*)idxp + 33024); // compacted V (16-B aligned)

    cvt3<<<4096, 256, 0, stream>>>(q, k, v, R0, R1, R2);
    cvtW<<<2048, 256, 0, stream>>>(Wq, Wk, Wv, Wo, Wb);
    maskScan<<<4, 256, 0, stream>>>(mk, idxp, nvp);
    gemm_bt<__hip_bfloat16><<<512, 256, 0, stream>>>(R0, Wb,          bq, R3, 8192, 1024, 1024, CSC);  // Qw=R3
    gemm_bt<__hip_bfloat16><<<512, 256, 0, stream>>>(R1, Wb + WN,     bk, R0, 8192, 1024, 1024, 1.0f); // Kw=R0
    gemm_bt<__hip_bfloat16><<<512, 256, 0, stream>>>(R2, Wb + 2 * WN, bv, R1, 8192, 1024, 1024, 1.0f); // Vw=R1
    gatherKV<<<128, 256, 0, stream>>>(R0, R1, idxp, nvp, R2, Vc);                                       // Kc=R2
    attn_kernel<<<1024, 256, 0, stream>>>(R3, R2, Vc, nvp, R0);                                         // Ow=R0
    gemm_bt<float><<<512, 256, 0, stream>>>(R0, Wb + 3 * WN, bo, out, 8192, 1024, 1024, 1.0f);
}

// Round 14
// 230.504 us; speedup vs baseline: 1.7105x; 1.0318x over previous
//
#include <hip/hip_runtime.h>
#include <hip/hip_bf16.h>

typedef short bh8 __attribute__((ext_vector_type(8)));      // 8 bf16 (4 VGPR) MFMA frag
typedef float f32x4 __attribute__((ext_vector_type(4)));
typedef float f32x16 __attribute__((ext_vector_type(16)));
typedef float f2 __attribute__((ext_vector_type(2)));
typedef unsigned int uint4v __attribute__((ext_vector_type(4)));

#define GLOBAL_P(p) ((const __attribute__((address_space(1))) void*)(p))
#define LDS_P(p)    ((__attribute__((address_space(3))) void*)(p))

__device__ inline bh8 pack8(const float4& a, const float4& b) {
    union { bh8 v; __hip_bfloat16 h[8]; } u;
    u.h[0] = __float2bfloat16(a.x); u.h[1] = __float2bfloat16(a.y);
    u.h[2] = __float2bfloat16(a.z); u.h[3] = __float2bfloat16(a.w);
    u.h[4] = __float2bfloat16(b.x); u.h[5] = __float2bfloat16(b.y);
    u.h[6] = __float2bfloat16(b.z); u.h[7] = __float2bfloat16(b.w);
    return u.v;
}

// ---------------------------------------------------------------------------
// cvt1: f32 -> bf16, one tensor. 8 elems/thread.
// ---------------------------------------------------------------------------
__global__ __launch_bounds__(256) void cvt1(
    const float* __restrict__ a, __hip_bfloat16* __restrict__ oa)
{
    size_t i = ((size_t)blockIdx.x * 256 + threadIdx.x) * 8;
    float4 x0 = *(const float4*)(a + i), x1 = *(const float4*)(a + i + 4);
    *(bh8*)(oa + i) = pack8(x0, x1);
}

// cvtW: 4 weight matrices f32 -> bf16 into one contiguous ws region.
__global__ __launch_bounds__(256) void cvtW(
    const float* __restrict__ a, const float* __restrict__ b,
    const float* __restrict__ c, const float* __restrict__ d,
    __hip_bfloat16* __restrict__ o)
{
    int seg = blockIdx.x >> 9;                       // 512 blocks per 1M-elem segment
    const float* src = (seg == 0) ? a : (seg == 1) ? b : (seg == 2) ? c : d;
    size_t i = ((size_t)(blockIdx.x & 511) * 256 + threadIdx.x) * 8;
    float4 x0 = *(const float4*)(src + i), x1 = *(const float4*)(src + i + 4);
    *(bh8*)(o + (size_t)seg * 1048576 + i) = pack8(x0, x1);
}

// ---------------------------------------------------------------------------
// maskScan: per batch, exclusive-scan the valid mask -> compact index list
// idx[b][pos] = kv, nv[b] = count. 4 blocks x 256 thr, 8 mask vals/thread.
// ---------------------------------------------------------------------------
__global__ __launch_bounds__(256) void maskScan(
    const int* __restrict__ mask, int* __restrict__ idx, int* __restrict__ nv)
{
    __shared__ int ts[256];
    const int b = blockIdx.x, tid = threadIdx.x;
    int f[8], cnt = 0;
#pragma unroll
    for (int j = 0; j < 8; ++j) {
        f[j] = (mask[b * 2048 + tid * 8 + j] != 0) ? 1 : 0;
        cnt += f[j];
    }
    ts[tid] = cnt;
    __syncthreads();
    for (int off = 1; off < 256; off <<= 1) {
        int v = (tid >= off) ? ts[tid - off] : 0;
        __syncthreads();
        ts[tid] += v;
        __syncthreads();
    }
    int base = ts[tid] - cnt;   // exclusive prefix
#pragma unroll
    for (int j = 0; j < 8; ++j)
        if (f[j]) idx[b * 2048 + base++] = tid * 8 + j;
    if (tid == 255) nv[b] = ts[255];
}

// ---------------------------------------------------------------------------
// gatherTok: compact VALID k,v token rows (f32 source, fused cvt to bf16)
// into per-batch-compacted buffers; zero-pad rows [n, npad128).
// Grid 128 = 4b x 32 row-blocks; 4 threads/row, 256 f32/thread per tensor.
// ---------------------------------------------------------------------------
__global__ __launch_bounds__(256) void gatherTok(
    const float* __restrict__ kf, const float* __restrict__ vf,
    const int* __restrict__ idx, const int* __restrict__ nv,
    __hip_bfloat16* __restrict__ kc, __hip_bfloat16* __restrict__ vc)
{
    const int b = blockIdx.x >> 5, rb = blockIdx.x & 31;
    const int n = nv[b], np = (n + 127) & ~127;
    const int r = rb * 64 + (threadIdx.x >> 2);
    if (r >= np) return;
    const int c0 = (threadIdx.x & 3) * 256;
    bh8* dk = (bh8*)(kc + ((size_t)b * 2048 + r) * 1024 + c0);
    bh8* dv = (bh8*)(vc + ((size_t)b * 2048 + r) * 1024 + c0);
    if (r < n) {
        const int s = idx[b * 2048 + r];
        const float4* sk = (const float4*)(kf + ((size_t)b * 2048 + s) * 1024 + c0);
        const float4* sv = (const float4*)(vf + ((size_t)b * 2048 + s) * 1024 + c0);
#pragma unroll
        for (int i = 0; i < 32; ++i) {
            dk[i] = pack8(sk[2 * i], sk[2 * i + 1]);
            dv[i] = pack8(sv[2 * i], sv[2 * i + 1]);
        }
    } else {
        bh8 z = {};
#pragma unroll
        for (int i = 0; i < 32; ++i) { dk[i] = z; dv[i] = z; }
    }
}

// ---------------------------------------------------------------------------
// GEMM: C[M,N] = (A[M,K] @ W[N,K]^T + bias) * oscale. A,W bf16, bias f32,
// C f32 or bf16. 128x128 tile, BK=64, 4 waves, mfma_f32_16x16x32_bf16,
// both operands staged via global_load_lds width=16 (m97 structure).
// COMPACT=true: M = 4 batches x 2048; row-block bm -> (batch=bm>>4, loc=bm&15);
// blocks with loc*128 >= npad128(batch) exit early (uniform, pre-barrier).
// ---------------------------------------------------------------------------
template <typename TC, bool COMPACT>
__global__ __launch_bounds__(256) void gemm_bt(
    const __hip_bfloat16* __restrict__ A, const __hip_bfloat16* __restrict__ W,
    const float* __restrict__ bias, TC* __restrict__ C,
    int M, int N, int Ksz, float oscale, const int* __restrict__ nvp)
{
    __shared__ __hip_bfloat16 As[128 * 64];
    __shared__ __hip_bfloat16 Bs[128 * 64];
    const int tid = threadIdx.x;
    const int l = tid & 63, w = tid >> 6;
    const int g4 = l >> 4, rl = l & 15;
    const int nb = N >> 7;
    const int bm = blockIdx.x / nb, bn = blockIdx.x % nb;
    if constexpr (COMPACT) {
        const int np = (nvp[bm >> 4] + 127) & ~127;
        if ((bm & 15) * 128 >= np) return;   // whole block exits (no barriers yet)
    }
    const long m0 = (long)bm * 128, n0 = (long)bn * 128;

    const __hip_bfloat16* ag[4];
    const __hip_bfloat16* wg[4];
    int ldsbase[4];
#pragma unroll
    for (int i = 0; i < 4; ++i) {
        int c = i * 256 + tid;           // chunk 0..1023
        int row = c >> 3, c8 = c & 7;
        ag[i] = A + (m0 + row) * Ksz + c8 * 8;
        wg[i] = W + (n0 + row) * Ksz + c8 * 8;
        ldsbase[i] = (i * 256 + w * 64) * 8;  // wave-uniform glds base (elements)
    }

    const int wr = w >> 1, wc = w & 1;
    f32x4 acc[4][4];
#pragma unroll
    for (int i = 0; i < 4; ++i)
#pragma unroll
        for (int j = 0; j < 4; ++j) acc[i][j] = f32x4{0.f, 0.f, 0.f, 0.f};

    const int nk = Ksz >> 6;
    for (int t = 0; t < nk; ++t) {
        __syncthreads();   // previous tile's LDS reads complete
#pragma unroll
        for (int i = 0; i < 4; ++i) {
            __builtin_amdgcn_global_load_lds(GLOBAL_P(ag[i]), LDS_P((__hip_bfloat16*)As + ldsbase[i]), 16, 0, 0);
            __builtin_amdgcn_global_load_lds(GLOBAL_P(wg[i]), LDS_P((__hip_bfloat16*)Bs + ldsbase[i]), 16, 0, 0);
            ag[i] += 64; wg[i] += 64;
        }
        __syncthreads();   // staged (barrier drains vmcnt)
#pragma unroll
        for (int kc = 0; kc < 2; ++kc) {
            bh8 af[4], bf[4];
#pragma unroll
            for (int mt = 0; mt < 4; ++mt) {
                int row = wr * 64 + mt * 16 + rl;
                af[mt] = *(const bh8*)(As + row * 64 + 8 * g4 + 32 * kc);
            }
#pragma unroll
            for (int nt = 0; nt < 4; ++nt) {
                int row = wc * 64 + nt * 16 + rl;
                bf[nt] = *(const bh8*)(Bs + row * 64 + 8 * g4 + 32 * kc);
            }
#pragma unroll
            for (int mt = 0; mt < 4; ++mt)
#pragma unroll
                for (int nt = 0; nt < 4; ++nt)
                    acc[mt][nt] = __builtin_amdgcn_mfma_f32_16x16x32_bf16(af[mt], bf[nt], acc[mt][nt], 0, 0, 0);
        }
    }

    // epilogue: (acc + bias) * oscale. C/D: col=lane&15, row=(lane>>4)*4+reg
    float bv[4];
#pragma unroll
    for (int nt = 0; nt < 4; ++nt)
        bv[nt] = bias[n0 + wc * 64 + nt * 16 + rl];
#pragma unroll
    for (int mt = 0; mt < 4; ++mt) {
#pragma unroll
        for (int r = 0; r < 4; ++r) {
            long row = m0 + wr * 64 + mt * 16 + g4 * 4 + r;
            TC* cp = C + row * N + n0 + wc * 64 + rl;
#pragma unroll
            for (int nt = 0; nt < 4; ++nt) {
                float x = (acc[mt][nt][r] + bv[nt]) * oscale;
                if constexpr (__is_same(TC, float)) cp[nt * 16] = x;
                else cp[nt * 16] = __float2bfloat16(x);
            }
        }
    }
}

// ---------------------------------------------------------------------------
// Flash attention over COMPACTED KV (valid columns only, zero-padded to x64).
// B=4 H=16 S=2048 D=64. Q pre-scaled by 0.125*log2(e). r8 structure:
// 4 waves x 32 q-rows (QB=128), KVBLK=64, nt=ceil(nv/64) iters (runtime),
// K via global_load_lds swizzle j^(r&7)^(r>>3); V reg->LDS transpose
// (paired u32 writes). Double-buffered; ONE barrier per iter. Swapped QK^T
// -> in-register softmax (log2, packed f32, half-row l_run, defer-max).
// Pad cols get bias -1e30 -> P=0 exactly (pad K/V rows = finite bias vecs).
// nt==0 (all-masked batch): loop skipped, l=0 -> O=0 (matches reference).
// ---------------------------------------------------------------------------
#define THRL 11.0f                 /* defer-max threshold, log2 units */

__global__ __launch_bounds__(256, 2) void attn_kernel(
    const __hip_bfloat16* __restrict__ Qm, const __hip_bfloat16* __restrict__ Km,
    const __hip_bfloat16* __restrict__ Vm, const int* __restrict__ nvp,
    __hip_bfloat16* __restrict__ Om)
{
    __shared__ __hip_bfloat16 Kt[2][64 * 64];   // K tile double buffer (xor-swizzled slots)
    __shared__ __hip_bfloat16 Vt[2][64 * 64];   // V^T double buffer (swizzled)
    __shared__ float biasS[2048];               // 0 for col<nv, -1e30 for pad
    const int tid = threadIdx.x;
    const int w = tid >> 6, l = tid & 63;
    const int G = l >> 5, c = l & 31;
    // XCD swizzle: xcd = id&7 owns bh = xcd*8 + (slot>>4); qb = slot&15
    const int id = blockIdx.x;
    const int xcd = id & 7, slot = id >> 3;
    const int bh = xcd * 8 + (slot >> 4);
    const int qb = slot & 15;
    const int b = bh >> 4, h = bh & 15;
    const int q0 = qb * 128 + w * 32;

    const int n = nvp[b];
    const int nt = (n + 63) >> 6;

#pragma unroll
    for (int i = 0; i < 8; ++i) {
        int idx = i * 256 + tid;
        biasS[idx] = (idx < n) ? 0.f : -1e30f;
    }

    // Q B-frags: col j = q = c, k = 8G+jj (+16*kc). (Q pre-scaled by CSC.)
    const __hip_bfloat16* qp = Qm + (size_t)(b * 2048 + q0 + c) * 1024 + h * 64 + 8 * G;
    bh8 qf[4];
#pragma unroll
    for (int kc = 0; kc < 4; ++kc) qf[kc] = *(const bh8*)(qp + 16 * kc);

    // K glds: LDS[r][8j] = global[r][8*(j ^ (r&7) ^ (r>>3))].
    // inst (w,i): rows r = 16w+8i+(l>>3); r&7 = l>>3, r>>3 = 2w+i (uniform).
    const int l38 = l >> 3, lc8 = l & 7;
    const __hip_bfloat16* kg0 = Km + (size_t)(b * 2048 + 16 * w + l38) * 1024 + h * 64 + 8 * ((lc8 ^ l38 ^ (2 * w)) & 7);
    const __hip_bfloat16* kg1 = Km + (size_t)(b * 2048 + 16 * w + 8 + l38) * 1024 + h * 64 + 8 * ((lc8 ^ l38 ^ (2 * w + 1)) & 7);
    const int kbase_e = w * 1024;               // LDS elem base for inst (w,0); (w,1): +512

    // V: thread owns rows {2vpi, 2vpi+1}, d-octet vd0..vd0+7
    const int vpi = tid >> 3, vd0 = (tid & 7) * 8;
    const __hip_bfloat16* vbase = Vm + (size_t)(b * 2048 + 2 * vpi) * 1024 + h * 64 + vd0;

    bh8 va0, va1;   // V rows 2vpi, 2vpi+1 of the prefetched tile
    auto loadV = [&](int tt) {
        const __hip_bfloat16* vp = vbase + (size_t)tt * 64 * 1024;
        va0 = *(const bh8*)vp;
        va1 = *(const bh8*)(vp + 1024);
    };
    auto stageV = [&](int buf) {
        __hip_bfloat16* dst = &Vt[buf][0];
#pragma unroll
        for (int j = 0; j < 8; ++j) {
            int d = vd0 + j;
            int swz = ((d & 7) ^ (d >> 3)) << 3;
            unsigned lo = (unsigned short)((const short*)&va0)[j];
            unsigned hi = (unsigned short)((const short*)&va1)[j];
            *(unsigned*)&dst[(d * 64 + 2 * vpi) ^ swz] = lo | (hi << 16);
        }
    };
    auto stageK = [&](int buf, int tt) {
        const size_t off = (size_t)tt * 64 * 1024;
        __builtin_amdgcn_global_load_lds(GLOBAL_P(kg0 + off), LDS_P(&Kt[buf][0] + kbase_e), 16, 0, 0);
        __builtin_amdgcn_global_load_lds(GLOBAL_P(kg1 + off), LDS_P(&Kt[buf][0] + kbase_e + 512), 16, 0, 0);
    };

    // prologue: K(0)->Kt[0]; V(0)->Vt[0]; V(1)->regs (clamped; in-bounds since
    // the compact buffer spans 2048 rows)
    stageK(0, 0);
    loadV(0);
    stageV(0);
    loadV(nt > 1 ? 1 : 0);
    __syncthreads();   // drains glds + LDS writes

    f32x16 o0 = {0.f}, o1 = {0.f};
    float m_run = -1e29f, l_run = 0.f;   // l_run is HALF-row (this lane's share)

    for (int t = 0; t < nt; ++t) {
        const int buf = t & 1;
        // stage next tile into buf^1; prefetch V(t+2) into regs
        if (t < nt - 1) {
            stageK(buf ^ 1, t + 1);
            stageV(buf ^ 1);               // va regs hold V(t+1)
            loadV(t + 2 < nt ? t + 2 : nt - 1);
        }
        __builtin_amdgcn_sched_barrier(0);

        // QK^T from LDS: S^T tiles D[i=kv-32ct][j=q], frag rows kv=32ct+c
        const __hip_bfloat16* kbuf = &Kt[buf][0];
        const int kx0 = ((c & 7) ^ (c >> 3)) << 3;   // row c swizzle
        const int kx1 = kx0 ^ 32;                    // row c+32: (r>>3) gains bit 2
        f32x16 s0 = {0.f}, s1 = {0.f};
        __builtin_amdgcn_s_setprio(1);
#pragma unroll
        for (int kc = 0; kc < 4; ++kc) {
            bh8 kf = *(const bh8*)(kbuf + c * 64 + ((16 * kc + 8 * G) ^ kx0));
            s0 = __builtin_amdgcn_mfma_f32_32x32x16_bf16(kf, qf[kc], s0, 0, 0, 0);
        }
#pragma unroll
        for (int kc = 0; kc < 4; ++kc) {
            bh8 kf = *(const bh8*)(kbuf + (c + 32) * 64 + ((16 * kc + 8 * G) ^ kx1));
            s1 = __builtin_amdgcn_mfma_f32_32x32x16_bf16(kf, qf[kc], s1, 0, 0, 0);
        }
        __builtin_amdgcn_s_setprio(0);

        // + pad bias, lane-local max (packed f32); Q already carries scale
        f2 mx2 = {-1e30f, -1e30f};
#pragma unroll
        for (int ct = 0; ct < 2; ++ct) {
            f2* sp = (f2*)(ct ? &s1 : &s0);
#pragma unroll
            for (int i2 = 0; i2 < 8; ++i2) {
                const int i = i2 * 2;
                f2 bb = *(const f2*)&biasS[t * 64 + ct * 32 + (i >> 2) * 8 + 4 * G + (i & 3)];
                f2 sv = sp[i2] + bb;
                sp[i2] = sv;
                mx2 = __builtin_elementwise_max(mx2, sv);
            }
        }
        float mxl = fmaxf(mx2[0], mx2[1]);

        if (__all(mxl - m_run <= THRL)) {
            // defer-max: no rescale, P bounded by 2^THRL
            f2 ls2 = {0.f, 0.f};
            f2 m2 = {m_run, m_run};
#pragma unroll
            for (int ct = 0; ct < 2; ++ct) {
                f2* sp = (f2*)(ct ? &s1 : &s0);
#pragma unroll
                for (int i2 = 0; i2 < 8; ++i2) {
                    f2 e = sp[i2] - m2;
                    f2 p;
                    p[0] = __builtin_amdgcn_exp2f(e[0]);
                    p[1] = __builtin_amdgcn_exp2f(e[1]);
                    sp[i2] = p; ls2 += p;
                }
            }
            l_run += ls2[0] + ls2[1];
        } else {
            float mxf = fmaxf(mxl, __shfl_xor(mxl, 32));
            const float m_new = fmaxf(m_run, mxf);
            const float fac = __builtin_amdgcn_exp2f(m_run - m_new);
            f2 ls2 = {0.f, 0.f};
            f2 m2 = {m_new, m_new};
#pragma unroll
            for (int ct = 0; ct < 2; ++ct) {
                f2* sp = (f2*)(ct ? &s1 : &s0);
#pragma unroll
                for (int i2 = 0; i2 < 8; ++i2) {
                    f2 e = sp[i2] - m2;
                    f2 p;
                    p[0] = __builtin_amdgcn_exp2f(e[0]);
                    p[1] = __builtin_amdgcn_exp2f(e[1]);
                    sp[i2] = p; ls2 += p;
                }
            }
            l_run = l_run * fac + (ls2[0] + ls2[1]);
            m_run = m_new;
            f2 fc = {fac, fac};
            f2* o0p = (f2*)&o0; f2* o1p = (f2*)&o1;
#pragma unroll
            for (int i2 = 0; i2 < 8; ++i2) { o0p[i2] *= fc; o1p[i2] *= fc; }
        }

        // PV: O^T += mfma(V^T-frag, P^T-frag). P^T frag built in-register.
        const __hip_bfloat16* vbuf = &Vt[buf][0];
        const int swz0 = ((c & 7) ^ (c >> 3)) << 3;
        const int swz1 = ((c & 7) ^ ((c + 32) >> 3)) << 3;
#pragma unroll
        for (int sl = 0; sl < 4; ++sl) {
            const f32x16& ps = (sl < 2) ? s0 : s1;
            const int R0 = 8 * (sl & 1);
            unsigned a0, a1, b0, b1;
            asm("v_cvt_pk_bf16_f32 %0, %1, %2" : "=v"(a0) : "v"(ps[R0 + 0]), "v"(ps[R0 + 1]));
            asm("v_cvt_pk_bf16_f32 %0, %1, %2" : "=v"(a1) : "v"(ps[R0 + 2]), "v"(ps[R0 + 3]));
            asm("v_cvt_pk_bf16_f32 %0, %1, %2" : "=v"(b0) : "v"(ps[R0 + 4]), "v"(ps[R0 + 5]));
            asm("v_cvt_pk_bf16_f32 %0, %1, %2" : "=v"(b1) : "v"(ps[R0 + 6]), "v"(ps[R0 + 7]));
            asm("v_permlane32_swap_b32 %0, %1" : "+v"(a0), "+v"(b0));
            asm("v_permlane32_swap_b32 %0, %1" : "+v"(a1), "+v"(b1));
            uint4v pu = {a0, a1, b0, b1};
            bh8 pf = __builtin_bit_cast(bh8, pu);
            const int kvb = 16 * sl + 8 * G;
            bh8 vf0 = *(const bh8*)(vbuf + c * 64 + (kvb ^ swz0));
            bh8 vf1 = *(const bh8*)(vbuf + (c + 32) * 64 + (kvb ^ swz1));
            __builtin_amdgcn_s_setprio(1);
            o0 = __builtin_amdgcn_mfma_f32_32x32x16_bf16(vf0, pf, o0, 0, 0, 0);
            o1 = __builtin_amdgcn_mfma_f32_32x32x16_bf16(vf1, pf, o1, 0, 0, 0);
            __builtin_amdgcn_s_setprio(0);
        }

        __syncthreads();   // buf reads done; buf^1 staging drained
    }

    // epilogue: combine half-row sums, O = acc/l (l==0 -> 0), packed stores
    float l_tot = l_run + __shfl_xor(l_run, 32);
    float inv = (l_tot > 0.f) ? 1.f / l_tot : 0.f;
    __hip_bfloat16* op = Om + (size_t)(b * 2048 + q0 + c) * 1024 + h * 64 + 4 * G;
#pragma unroll
    for (int dt = 0; dt < 2; ++dt) {
#pragma unroll
        for (int rb = 0; rb < 4; ++rb) {
            union { ushort4 u; __hip_bfloat16 hv[4]; } cv;
#pragma unroll
            for (int j = 0; j < 4; ++j) {
                float x = (dt ? o1[rb * 4 + j] : o0[rb * 4 + j]) * inv;
                cv.hv[j] = __float2bfloat16(x);
            }
            *(ushort4*)(op + dt * 32 + rb * 8) = cv.u;
        }
    }
}

// ---------------------------------------------------------------------------
extern "C" void kernel_launch(void* const* d_in, const int* in_sizes, int n_in,
                              void* d_out, int out_size, void* d_ws, size_t ws_size,
                              hipStream_t stream) {
    const float* q  = (const float*)d_in[0];
    const float* k  = (const float*)d_in[1];
    const float* v  = (const float*)d_in[2];
    const int*   mk = (const int*)d_in[3];
    const float* Wq = (const float*)d_in[4];
    const float* bq = (const float*)d_in[5];
    const float* Wk = (const float*)d_in[6];
    const float* bk = (const float*)d_in[7];
    const float* Wv = (const float*)d_in[8];
    const float* bv = (const float*)d_in[9];
    const float* Wo = (const float*)d_in[10];
    const float* bo = (const float*)d_in[11];
    float* out = (float*)d_out;

    const float CSC = 0.18033688011112042f;      // 0.125 * log2(e), folded into Q
    const size_t MN = (size_t)8192 * 1024;
    const size_t WN = (size_t)1024 * 1024;
    // Region recycle plan (<= r13's proven footprint):
    __hip_bfloat16* R0 = (__hip_bfloat16*)d_ws;  // q_bf   -> Kc (K-proj out)
    __hip_bfloat16* R1 = R0 + MN;                // kc_in  -> Vc (V-proj out)
    __hip_bfloat16* R2 = R1 + MN;                // vc_in  -> Ow (attn out)
    __hip_bfloat16* R3 = R2 + MN;                // Qw (pre-scaled)
    __hip_bfloat16* Wb = R3 + MN;                // Wq,Wk,Wv,Wo bf16 (4 x 1M elems)
    int* idxp = (int*)(Wb + 4 * WN);             // [4][2048] compact indices
    int* nvp  = idxp + 4 * 2048;                 // [4] valid counts

    cvt1<<<4096, 256, 0, stream>>>(q, R0);                                   // q_bf = R0
    cvtW<<<2048, 256, 0, stream>>>(Wq, Wk, Wv, Wo, Wb);
    maskScan<<<4, 256, 0, stream>>>(mk, idxp, nvp);
    gatherTok<<<128, 256, 0, stream>>>(k, v, idxp, nvp, R1, R2);             // kc_in=R1, vc_in=R2
    gemm_bt<__hip_bfloat16, false><<<512, 256, 0, stream>>>(R0, Wb,          bq, R3, 8192, 1024, 1024, CSC,  nullptr); // Qw=R3
    gemm_bt<__hip_bfloat16, true ><<<512, 256, 0, stream>>>(R1, Wb + WN,     bk, R0, 8192, 1024, 1024, 1.0f, nvp);     // Kc=R0
    gemm_bt<__hip_bfloat16, true ><<<512, 256, 0, stream>>>(R2, Wb + 2 * WN, bv, R1, 8192, 1024, 1024, 1.0f, nvp);     // Vc=R1
    attn_kernel<<<1024, 256, 0, stream>>>(R3, R0, R1, nvp, R2);                                                         // Ow=R2
    gemm_bt<float, false><<<512, 256, 0, stream>>>(R2, Wb + 3 * WN, bo, out, 8192, 1024, 1024, 1.0f, nullptr);
}

// Round 15
// 203.817 us; speedup vs baseline: 1.9344x; 1.1309x over previous
//
#include <hip/hip_runtime.h>
#include <hip/hip_bf16.h>

typedef short bh8 __attribute__((ext_vector_type(8)));      // 8 bf16 (4 VGPR) MFMA frag
typedef float f32x4 __attribute__((ext_vector_type(4)));
typedef float f32x16 __attribute__((ext_vector_type(16)));
typedef float f2 __attribute__((ext_vector_type(2)));
typedef unsigned int uint4v __attribute__((ext_vector_type(4)));

#define GLOBAL_P(p) ((const __attribute__((address_space(1))) void*)(p))
#define LDS_P(p)    ((__attribute__((address_space(3))) void*)(p))

__device__ inline bh8 pack8(const float4& a, const float4& b) {
    union { bh8 v; __hip_bfloat16 h[8]; } u;
    u.h[0] = __float2bfloat16(a.x); u.h[1] = __float2bfloat16(a.y);
    u.h[2] = __float2bfloat16(a.z); u.h[3] = __float2bfloat16(a.w);
    u.h[4] = __float2bfloat16(b.x); u.h[5] = __float2bfloat16(b.y);
    u.h[6] = __float2bfloat16(b.z); u.h[7] = __float2bfloat16(b.w);
    return u.v;
}

// ---------------------------------------------------------------------------
// prep: fused {q f32->bf16 (4096 blocks), W f32->bf16 (2048), maskScan (4)}.
// ---------------------------------------------------------------------------
__global__ __launch_bounds__(256) void prep(
    const float* __restrict__ q, const float* __restrict__ Wq,
    const float* __restrict__ Wk, const float* __restrict__ Wv,
    const float* __restrict__ Wo, const int* __restrict__ mask,
    __hip_bfloat16* __restrict__ qbf, __hip_bfloat16* __restrict__ Wb,
    int* __restrict__ idx, int* __restrict__ nv)
{
    __shared__ int ts[256];
    const int bid = blockIdx.x, tid = threadIdx.x;
    if (bid < 4096) {
        size_t i = ((size_t)bid * 256 + tid) * 8;
        float4 x0 = *(const float4*)(q + i), x1 = *(const float4*)(q + i + 4);
        *(bh8*)(qbf + i) = pack8(x0, x1);
    } else if (bid < 6144) {
        const int sb = bid - 4096;
        const int seg = sb >> 9;
        const float* src = (seg == 0) ? Wq : (seg == 1) ? Wk : (seg == 2) ? Wv : Wo;
        size_t i = ((size_t)(sb & 511) * 256 + tid) * 8;
        float4 x0 = *(const float4*)(src + i), x1 = *(const float4*)(src + i + 4);
        *(bh8*)(Wb + (size_t)seg * 1048576 + i) = pack8(x0, x1);
    } else {
        const int b = bid - 6144;
        int f[8], cnt = 0;
#pragma unroll
        for (int j = 0; j < 8; ++j) {
            f[j] = (mask[b * 2048 + tid * 8 + j] != 0) ? 1 : 0;
            cnt += f[j];
        }
        ts[tid] = cnt;
        __syncthreads();
        for (int off = 1; off < 256; off <<= 1) {
            int v = (tid >= off) ? ts[tid - off] : 0;
            __syncthreads();
            ts[tid] += v;
            __syncthreads();
        }
        int base = ts[tid] - cnt;   // exclusive prefix
#pragma unroll
        for (int j = 0; j < 8; ++j)
            if (f[j]) idx[b * 2048 + base++] = tid * 8 + j;
        if (tid == 255) nv[b] = ts[255];
    }
}

// ---------------------------------------------------------------------------
// gatherTok: compact VALID k,v token rows (f32 source, fused cvt to bf16);
// zero-pad rows [n, npad128). Grid 512 = 4b x 128 row-blocks (16 rows each),
// 16 threads/row, 64 f32/thread per tensor.
// ---------------------------------------------------------------------------
__global__ __launch_bounds__(256) void gatherTok(
    const float* __restrict__ kf, const float* __restrict__ vf,
    const int* __restrict__ idx, const int* __restrict__ nv,
    __hip_bfloat16* __restrict__ kc, __hip_bfloat16* __restrict__ vc)
{
    const int b = blockIdx.x >> 7, rb = blockIdx.x & 127;
    const int n = nv[b], np = (n + 127) & ~127;
    const int r = rb * 16 + (threadIdx.x >> 4);
    if (r >= np) return;
    const int c0 = (threadIdx.x & 15) * 64;
    bh8* dk = (bh8*)(kc + ((size_t)b * 2048 + r) * 1024 + c0);
    bh8* dv = (bh8*)(vc + ((size_t)b * 2048 + r) * 1024 + c0);
    if (r < n) {
        const int s = idx[b * 2048 + r];
        const float4* sk = (const float4*)(kf + ((size_t)b * 2048 + s) * 1024 + c0);
        const float4* sv = (const float4*)(vf + ((size_t)b * 2048 + s) * 1024 + c0);
#pragma unroll
        for (int i = 0; i < 8; ++i) {
            dk[i] = pack8(sk[2 * i], sk[2 * i + 1]);
            dv[i] = pack8(sv[2 * i], sv[2 * i + 1]);
        }
    } else {
        bh8 z = {};
#pragma unroll
        for (int i = 0; i < 8; ++i) { dk[i] = z; dv[i] = z; }
    }
}

// ---------------------------------------------------------------------------
// gemm_core: C[128x128 tile] = (A @ W^T + bias) * oscale. m97 structure.
// COMPACT: M = 4 batches x 2048; blocks past npad128(batch) exit early.
// ---------------------------------------------------------------------------
template <typename TC, bool COMPACT>
__device__ __forceinline__ void gemm_core(
    const __hip_bfloat16* __restrict__ A, const __hip_bfloat16* __restrict__ W,
    const float* __restrict__ bias, TC* __restrict__ C,
    int N, int Ksz, float oscale, const int* __restrict__ nvp,
    int bm, int bn, __hip_bfloat16* As, __hip_bfloat16* Bs)
{
    if constexpr (COMPACT) {
        const int np = (nvp[bm >> 4] + 127) & ~127;
        if ((bm & 15) * 128 >= np) return;   // whole block exits (no barriers yet)
    }
    const int tid = threadIdx.x;
    const int l = tid & 63, w = tid >> 6;
    const int g4 = l >> 4, rl = l & 15;
    const long m0 = (long)bm * 128, n0 = (long)bn * 128;

    const __hip_bfloat16* ag[4];
    const __hip_bfloat16* wg[4];
    int ldsbase[4];
#pragma unroll
    for (int i = 0; i < 4; ++i) {
        int c = i * 256 + tid;           // chunk 0..1023
        int row = c >> 3, c8 = c & 7;
        ag[i] = A + (m0 + row) * Ksz + c8 * 8;
        wg[i] = W + (n0 + row) * Ksz + c8 * 8;
        ldsbase[i] = (i * 256 + w * 64) * 8;  // wave-uniform glds base (elements)
    }

    const int wr = w >> 1, wc = w & 1;
    f32x4 acc[4][4];
#pragma unroll
    for (int i = 0; i < 4; ++i)
#pragma unroll
        for (int j = 0; j < 4; ++j) acc[i][j] = f32x4{0.f, 0.f, 0.f, 0.f};

    const int nk = Ksz >> 6;
    for (int t = 0; t < nk; ++t) {
        __syncthreads();   // previous tile's LDS reads complete
#pragma unroll
        for (int i = 0; i < 4; ++i) {
            __builtin_amdgcn_global_load_lds(GLOBAL_P(ag[i]), LDS_P(As + ldsbase[i]), 16, 0, 0);
            __builtin_amdgcn_global_load_lds(GLOBAL_P(wg[i]), LDS_P(Bs + ldsbase[i]), 16, 0, 0);
            ag[i] += 64; wg[i] += 64;
        }
        __syncthreads();   // staged (barrier drains vmcnt)
#pragma unroll
        for (int kc = 0; kc < 2; ++kc) {
            bh8 af[4], bf[4];
#pragma unroll
            for (int mt = 0; mt < 4; ++mt) {
                int row = wr * 64 + mt * 16 + rl;
                af[mt] = *(const bh8*)(As + row * 64 + 8 * g4 + 32 * kc);
            }
#pragma unroll
            for (int nt = 0; nt < 4; ++nt) {
                int row = wc * 64 + nt * 16 + rl;
                bf[nt] = *(const bh8*)(Bs + row * 64 + 8 * g4 + 32 * kc);
            }
#pragma unroll
            for (int mt = 0; mt < 4; ++mt)
#pragma unroll
                for (int nt = 0; nt < 4; ++nt)
                    acc[mt][nt] = __builtin_amdgcn_mfma_f32_16x16x32_bf16(af[mt], bf[nt], acc[mt][nt], 0, 0, 0);
        }
    }

    // epilogue: (acc + bias) * oscale. C/D: col=lane&15, row=(lane>>4)*4+reg
    float bv[4];
#pragma unroll
    for (int nt = 0; nt < 4; ++nt)
        bv[nt] = bias[n0 + wc * 64 + nt * 16 + rl];
#pragma unroll
    for (int mt = 0; mt < 4; ++mt) {
#pragma unroll
        for (int r = 0; r < 4; ++r) {
            long row = m0 + wr * 64 + mt * 16 + g4 * 4 + r;
            TC* cp = C + row * N + n0 + wc * 64 + rl;
#pragma unroll
            for (int nt = 0; nt < 4; ++nt) {
                float x = (acc[mt][nt][r] + bv[nt]) * oscale;
                if constexpr (__is_same(TC, float)) cp[nt * 16] = x;
                else cp[nt * 16] = __float2bfloat16(x);
            }
        }
    }
}

template <typename TC, bool COMPACT>
__global__ __launch_bounds__(256) void gemm_bt(
    const __hip_bfloat16* __restrict__ A, const __hip_bfloat16* __restrict__ W,
    const float* __restrict__ bias, TC* __restrict__ C,
    int N, int Ksz, float oscale, const int* __restrict__ nvp)
{
    __shared__ __hip_bfloat16 As[128 * 64];
    __shared__ __hip_bfloat16 Bs[128 * 64];
    const int nb = N >> 7;
    gemm_core<TC, COMPACT>(A, W, bias, C, N, Ksz, oscale, nvp,
                           blockIdx.x / nb, blockIdx.x % nb, As, Bs);
}

// Fused Q-proj (blocks 0..511) + K-proj (blocks 512..1023, compact-exit).
__global__ __launch_bounds__(256) void gemm_projqk(
    const __hip_bfloat16* __restrict__ Aq, const __hip_bfloat16* __restrict__ Ak,
    const __hip_bfloat16* __restrict__ Wb, const float* __restrict__ bq,
    const float* __restrict__ bk, __hip_bfloat16* __restrict__ Cq,
    __hip_bfloat16* __restrict__ Ck, const int* __restrict__ nvp, float csc)
{
    __shared__ __hip_bfloat16 As[128 * 64];
    __shared__ __hip_bfloat16 Bs[128 * 64];
    const int bid = blockIdx.x;
    if (bid < 512)
        gemm_core<__hip_bfloat16, false>(Aq, Wb, bq, Cq, 1024, 1024, csc, nullptr,
                                         bid >> 3, bid & 7, As, Bs);
    else
        gemm_core<__hip_bfloat16, true>(Ak, Wb + 1048576, bk, Ck, 1024, 1024, 1.0f, nvp,
                                        (bid - 512) >> 3, bid & 7, As, Bs);
}

// ---------------------------------------------------------------------------
// Flash attention over COMPACTED KV (valid columns only, zero-padded to x64).
// B=4 H=16 S=2048 D=64. Q pre-scaled by 0.125*log2(e). r8 structure:
// 4 waves x 32 q-rows (QB=128), KVBLK=64, nt=ceil(nv/64) iters (runtime),
// K via global_load_lds swizzle j^(r&7)^(r>>3); V reg->LDS transpose
// (paired u32 writes). Double-buffered; ONE barrier per iter. Swapped QK^T
// -> in-register softmax (log2, packed f32, half-row l_run, defer-max).
// Pad cols get bias -1e30 -> P=0 exactly (pad K/V rows = finite bias vecs).
// nt==0 (all-masked batch): loop skipped, l=0 -> O=0 (matches reference).
// ---------------------------------------------------------------------------
#define THRL 11.0f                 /* defer-max threshold, log2 units */

__global__ __launch_bounds__(256, 2) void attn_kernel(
    const __hip_bfloat16* __restrict__ Qm, const __hip_bfloat16* __restrict__ Km,
    const __hip_bfloat16* __restrict__ Vm, const int* __restrict__ nvp,
    __hip_bfloat16* __restrict__ Om)
{
    __shared__ __hip_bfloat16 Kt[2][64 * 64];   // K tile double buffer (xor-swizzled slots)
    __shared__ __hip_bfloat16 Vt[2][64 * 64];   // V^T double buffer (swizzled)
    __shared__ float biasS[2048];               // 0 for col<nv, -1e30 for pad
    const int tid = threadIdx.x;
    const int w = tid >> 6, l = tid & 63;
    const int G = l >> 5, c = l & 31;
    // XCD swizzle: xcd = id&7 owns bh = xcd*8 + (slot>>4); qb = slot&15
    const int id = blockIdx.x;
    const int xcd = id & 7, slot = id >> 3;
    const int bh = xcd * 8 + (slot >> 4);
    const int qb = slot & 15;
    const int b = bh >> 4, h = bh & 15;
    const int q0 = qb * 128 + w * 32;

    const int n = nvp[b];
    const int nt = (n + 63) >> 6;

#pragma unroll
    for (int i = 0; i < 8; ++i) {
        int idx = i * 256 + tid;
        biasS[idx] = (idx < n) ? 0.f : -1e30f;
    }

    // Q B-frags: col j = q = c, k = 8G+jj (+16*kc). (Q pre-scaled by CSC.)
    const __hip_bfloat16* qp = Qm + (size_t)(b * 2048 + q0 + c) * 1024 + h * 64 + 8 * G;
    bh8 qf[4];
#pragma unroll
    for (int kc = 0; kc < 4; ++kc) qf[kc] = *(const bh8*)(qp + 16 * kc);

    // K glds: LDS[r][8j] = global[r][8*(j ^ (r&7) ^ (r>>3))].
    // inst (w,i): rows r = 16w+8i+(l>>3); r&7 = l>>3, r>>3 = 2w+i (uniform).
    const int l38 = l >> 3, lc8 = l & 7;
    const __hip_bfloat16* kg0 = Km + (size_t)(b * 2048 + 16 * w + l38) * 1024 + h * 64 + 8 * ((lc8 ^ l38 ^ (2 * w)) & 7);
    const __hip_bfloat16* kg1 = Km + (size_t)(b * 2048 + 16 * w + 8 + l38) * 1024 + h * 64 + 8 * ((lc8 ^ l38 ^ (2 * w + 1)) & 7);
    const int kbase_e = w * 1024;               // LDS elem base for inst (w,0); (w,1): +512

    // V: thread owns rows {2vpi, 2vpi+1}, d-octet vd0..vd0+7
    const int vpi = tid >> 3, vd0 = (tid & 7) * 8;
    const __hip_bfloat16* vbase = Vm + (size_t)(b * 2048 + 2 * vpi) * 1024 + h * 64 + vd0;

    bh8 va0, va1;   // V rows 2vpi, 2vpi+1 of the prefetched tile
    auto loadV = [&](int tt) {
        const __hip_bfloat16* vp = vbase + (size_t)tt * 64 * 1024;
        va0 = *(const bh8*)vp;
        va1 = *(const bh8*)(vp + 1024);
    };
    auto stageV = [&](int buf) {
        __hip_bfloat16* dst = &Vt[buf][0];
#pragma unroll
        for (int j = 0; j < 8; ++j) {
            int d = vd0 + j;
            int swz = ((d & 7) ^ (d >> 3)) << 3;
            unsigned lo = (unsigned short)((const short*)&va0)[j];
            unsigned hi = (unsigned short)((const short*)&va1)[j];
            *(unsigned*)&dst[(d * 64 + 2 * vpi) ^ swz] = lo | (hi << 16);
        }
    };
    auto stageK = [&](int buf, int tt) {
        const size_t off = (size_t)tt * 64 * 1024;
        __builtin_amdgcn_global_load_lds(GLOBAL_P(kg0 + off), LDS_P(&Kt[buf][0] + kbase_e), 16, 0, 0);
        __builtin_amdgcn_global_load_lds(GLOBAL_P(kg1 + off), LDS_P(&Kt[buf][0] + kbase_e + 512), 16, 0, 0);
    };

    // prologue: K(0)->Kt[0]; V(0)->Vt[0]; V(1)->regs (clamped; in-bounds since
    // the compact buffer spans 2048 rows)
    stageK(0, 0);
    loadV(0);
    stageV(0);
    loadV(nt > 1 ? 1 : 0);
    __syncthreads();   // drains glds + LDS writes

    f32x16 o0 = {0.f}, o1 = {0.f};
    float m_run = -1e29f, l_run = 0.f;   // l_run is HALF-row (this lane's share)

    for (int t = 0; t < nt; ++t) {
        const int buf = t & 1;
        // stage next tile into buf^1; prefetch V(t+2) into regs
        if (t < nt - 1) {
            stageK(buf ^ 1, t + 1);
            stageV(buf ^ 1);               // va regs hold V(t+1)
            loadV(t + 2 < nt ? t + 2 : nt - 1);
        }
        __builtin_amdgcn_sched_barrier(0);

        // QK^T from LDS: S^T tiles D[i=kv-32ct][j=q], frag rows kv=32ct+c
        const __hip_bfloat16* kbuf = &Kt[buf][0];
        const int kx0 = ((c & 7) ^ (c >> 3)) << 3;   // row c swizzle
        const int kx1 = kx0 ^ 32;                    // row c+32: (r>>3) gains bit 2
        f32x16 s0 = {0.f}, s1 = {0.f};
        __builtin_amdgcn_s_setprio(1);
#pragma unroll
        for (int kc = 0; kc < 4; ++kc) {
            bh8 kf = *(const bh8*)(kbuf + c * 64 + ((16 * kc + 8 * G) ^ kx0));
            s0 = __builtin_amdgcn_mfma_f32_32x32x16_bf16(kf, qf[kc], s0, 0, 0, 0);
        }
#pragma unroll
        for (int kc = 0; kc < 4; ++kc) {
            bh8 kf = *(const bh8*)(kbuf + (c + 32) * 64 + ((16 * kc + 8 * G) ^ kx1));
            s1 = __builtin_amdgcn_mfma_f32_32x32x16_bf16(kf, qf[kc], s1, 0, 0, 0);
        }
        __builtin_amdgcn_s_setprio(0);

        // + pad bias, lane-local max (packed f32); Q already carries scale
        f2 mx2 = {-1e30f, -1e30f};
#pragma unroll
        for (int ct = 0; ct < 2; ++ct) {
            f2* sp = (f2*)(ct ? &s1 : &s0);
#pragma unroll
            for (int i2 = 0; i2 < 8; ++i2) {
                const int i = i2 * 2;
                f2 bb = *(const f2*)&biasS[t * 64 + ct * 32 + (i >> 2) * 8 + 4 * G + (i & 3)];
                f2 sv = sp[i2] + bb;
                sp[i2] = sv;
                mx2 = __builtin_elementwise_max(mx2, sv);
            }
        }
        float mxl = fmaxf(mx2[0], mx2[1]);

        if (__all(mxl - m_run <= THRL)) {
            // defer-max: no rescale, P bounded by 2^THRL
            f2 ls2 = {0.f, 0.f};
            f2 m2 = {m_run, m_run};
#pragma unroll
            for (int ct = 0; ct < 2; ++ct) {
                f2* sp = (f2*)(ct ? &s1 : &s0);
#pragma unroll
                for (int i2 = 0; i2 < 8; ++i2) {
                    f2 e = sp[i2] - m2;
                    f2 p;
                    p[0] = __builtin_amdgcn_exp2f(e[0]);
                    p[1] = __builtin_amdgcn_exp2f(e[1]);
                    sp[i2] = p; ls2 += p;
                }
            }
            l_run += ls2[0] + ls2[1];
        } else {
            float mxf = fmaxf(mxl, __shfl_xor(mxl, 32));
            const float m_new = fmaxf(m_run, mxf);
            const float fac = __builtin_amdgcn_exp2f(m_run - m_new);
            f2 ls2 = {0.f, 0.f};
            f2 m2 = {m_new, m_new};
#pragma unroll
            for (int ct = 0; ct < 2; ++ct) {
                f2* sp = (f2*)(ct ? &s1 : &s0);
#pragma unroll
                for (int i2 = 0; i2 < 8; ++i2) {
                    f2 e = sp[i2] - m2;
                    f2 p;
                    p[0] = __builtin_amdgcn_exp2f(e[0]);
                    p[1] = __builtin_amdgcn_exp2f(e[1]);
                    sp[i2] = p; ls2 += p;
                }
            }
            l_run = l_run * fac + (ls2[0] + ls2[1]);
            m_run = m_new;
            f2 fc = {fac, fac};
            f2* o0p = (f2*)&o0; f2* o1p = (f2*)&o1;
#pragma unroll
            for (int i2 = 0; i2 < 8; ++i2) { o0p[i2] *= fc; o1p[i2] *= fc; }
        }

        // PV: O^T += mfma(V^T-frag, P^T-frag). P^T frag built in-register.
        const __hip_bfloat16* vbuf = &Vt[buf][0];
        const int swz0 = ((c & 7) ^ (c >> 3)) << 3;
        const int swz1 = ((c & 7) ^ ((c + 32) >> 3)) << 3;
#pragma unroll
        for (int sl = 0; sl < 4; ++sl) {
            const f32x16& ps = (sl < 2) ? s0 : s1;
            const int R0 = 8 * (sl & 1);
            unsigned a0, a1, b0, b1;
            asm("v_cvt_pk_bf16_f32 %0, %1, %2" : "=v"(a0) : "v"(ps[R0 + 0]), "v"(ps[R0 + 1]));
            asm("v_cvt_pk_bf16_f32 %0, %1, %2" : "=v"(a1) : "v"(ps[R0 + 2]), "v"(ps[R0 + 3]));
            asm("v_cvt_pk_bf16_f32 %0, %1, %2" : "=v"(b0) : "v"(ps[R0 + 4]), "v"(ps[R0 + 5]));
            asm("v_cvt_pk_bf16_f32 %0, %1, %2" : "=v"(b1) : "v"(ps[R0 + 6]), "v"(ps[R0 + 7]));
            asm("v_permlane32_swap_b32 %0, %1" : "+v"(a0), "+v"(b0));
            asm("v_permlane32_swap_b32 %0, %1" : "+v"(a1), "+v"(b1));
            uint4v pu = {a0, a1, b0, b1};
            bh8 pf = __builtin_bit_cast(bh8, pu);
            const int kvb = 16 * sl + 8 * G;
            bh8 vf0 = *(const bh8*)(vbuf + c * 64 + (kvb ^ swz0));
            bh8 vf1 = *(const bh8*)(vbuf + (c + 32) * 64 + (kvb ^ swz1));
            __builtin_amdgcn_s_setprio(1);
            o0 = __builtin_amdgcn_mfma_f32_32x32x16_bf16(vf0, pf, o0, 0, 0, 0);
            o1 = __builtin_amdgcn_mfma_f32_32x32x16_bf16(vf1, pf, o1, 0, 0, 0);
            __builtin_amdgcn_s_setprio(0);
        }

        __syncthreads();   // buf reads done; buf^1 staging drained
    }

    // epilogue: combine half-row sums, O = acc/l (l==0 -> 0), packed stores
    float l_tot = l_run + __shfl_xor(l_run, 32);
    float inv = (l_tot > 0.f) ? 1.f / l_tot : 0.f;
    __hip_bfloat16* op = Om + (size_t)(b * 2048 + q0 + c) * 1024 + h * 64 + 4 * G;
#pragma unroll
    for (int dt = 0; dt < 2; ++dt) {
#pragma unroll
        for (int rb = 0; rb < 4; ++rb) {
            union { ushort4 u; __hip_bfloat16 hv[4]; } cv;
#pragma unroll
            for (int j = 0; j < 4; ++j) {
                float x = (dt ? o1[rb * 4 + j] : o0[rb * 4 + j]) * inv;
                cv.hv[j] = __float2bfloat16(x);
            }
            *(ushort4*)(op + dt * 32 + rb * 8) = cv.u;
        }
    }
}

// ---------------------------------------------------------------------------
extern "C" void kernel_launch(void* const* d_in, const int* in_sizes, int n_in,
                              void* d_out, int out_size, void* d_ws, size_t ws_size,
                              hipStream_t stream) {
    const float* q  = (const float*)d_in[0];
    const float* k  = (const float*)d_in[1];
    const float* v  = (const float*)d_in[2];
    const int*   mk = (const int*)d_in[3];
    const float* Wq = (const float*)d_in[4];
    const float* bq = (const float*)d_in[5];
    const float* Wk = (const float*)d_in[6];
    const float* bk = (const float*)d_in[7];
    const float* Wv = (const float*)d_in[8];
    const float* bv = (const float*)d_in[9];
    const float* Wo = (const float*)d_in[10];
    const float* bo = (const float*)d_in[11];
    float* out = (float*)d_out;

    const float CSC = 0.18033688011112042f;      // 0.125 * log2(e), folded into Q
    const size_t MN = (size_t)8192 * 1024;
    const size_t WN = (size_t)1024 * 1024;
    // Region plan (~92 MB, matches r12's proven footprint):
    __hip_bfloat16* R0 = (__hip_bfloat16*)d_ws;  // q_bf  -> Ow (attn out)
    __hip_bfloat16* R1 = R0 + MN;                // kc_in -> Vc (V-proj out)
    __hip_bfloat16* R2 = R1 + MN;                // vc_in
    __hip_bfloat16* R3 = R2 + MN;                // Qw (pre-scaled)
    __hip_bfloat16* Wb = R3 + MN;                // Wq,Wk,Wv,Wo bf16 (4 x 1M elems)
    int* idxp = (int*)(Wb + 4 * WN);             // [4][2048] compact indices
    int* nvp  = idxp + 4 * 2048;                 // [4] valid counts
    __hip_bfloat16* R4 = (__hip_bfloat16*)((char*)idxp + 33024);  // Kc (K-proj out)

    prep<<<6148, 256, 0, stream>>>(q, Wq, Wk, Wv, Wo, mk, R0, Wb, idxp, nvp);
    gatherTok<<<512, 256, 0, stream>>>(k, v, idxp, nvp, R1, R2);              // kc_in=R1, vc_in=R2
    gemm_projqk<<<1024, 256, 0, stream>>>(R0, R1, Wb, bq, bk, R3, R4, nvp, CSC); // Qw=R3, Kc=R4
    gemm_bt<__hip_bfloat16, true><<<512, 256, 0, stream>>>(R2, Wb + 2 * WN, bv, R1, 1024, 1024, 1.0f, nvp); // Vc=R1
    attn_kernel<<<1024, 256, 0, stream>>>(R3, R4, R1, nvp, R0);               // Ow=R0
    gemm_bt<float, false><<<512, 256, 0, stream>>>(R0, Wb + 3 * WN, bo, out, 1024, 1024, 1.0f, nullptr);
}